// Round 1
// baseline (14424.352 us; speedup 1.0000x reference)
//
#include <hip/hip_runtime.h>
#include <cmath>

// ---------------------------------------------------------------------------
// GCN_Message: graph VAE forward.
//   6x SAGEConv (mean aggr): out = mean_{j->i}(x_j) @ Wl^T + b + x_i @ Wr^T
//   plus dense layers tr2 / dec1 and a 3-wide dec4 head.
// Baseline strategy (round 1):
//   - degree count once per call (int atomics), inv = 1/max(cnt,1)
//   - aggregation: one thread per (edge, float4 chunk); float atomicAdd scatter
//   - node GEMM: 64-row tiles, W + A staged transposed in LDS, 4x8 reg tiles
// ---------------------------------------------------------------------------

constexpr int ACT_NONE = 0, ACT_TANH = 1, ACT_LEAKY = 2;

__global__ __launch_bounds__(256) void count_kernel(const int* __restrict__ dst,
                                                    int* __restrict__ cnt, int E) {
  int e = blockIdx.x * 256 + threadIdx.x;
  if (e < E) atomicAdd(&cnt[dst[e]], 1);
}

__global__ __launch_bounds__(256) void inv_kernel(const int* __restrict__ cnt,
                                                  float* __restrict__ inv, int n) {
  int i = blockIdx.x * 256 + threadIdx.x;
  if (i < n) {
    int c = cnt[i];
    inv[i] = 1.0f / (float)(c > 1 ? c : 1);
  }
}

// scatter-add x[src] into sumb[dst]; one thread per (edge, 4-float chunk)
template <int D>
__global__ __launch_bounds__(256) void agg_kernel(const float* __restrict__ in,
                                                  const int* __restrict__ src,
                                                  const int* __restrict__ dst,
                                                  float* __restrict__ sumb, int E) {
  constexpr int C = D / 4;
  int tid = blockIdx.x * 256 + threadIdx.x;
  int total = E * C;  // max 51.2M, fits int
  if (tid >= total) return;
  int e = tid / C;
  int c = tid - e * C;
  int s = src[e];
  int d = dst[e];
  const float4 v = *(const float4*)(in + (size_t)s * D + c * 4);
  float* dp = sumb + (size_t)d * D + c * 4;
  atomicAdd(dp + 0, v.x);
  atomicAdd(dp + 1, v.y);
  atomicAdd(dp + 2, v.z);
  atomicAdd(dp + 3, v.w);
}

// out[row, col] = act( (AGG ? mean@Wl^T : 0) + in@Wr^T + b ), 64-row blocks.
// LDS holds transposed chunks: As[kk][row], Ws[kk][col]; thread tile 4 rows x TN cols.
template <int DI, int DO, int ACT, bool AGG>
__global__ __launch_bounds__(256) void node_kernel(
    const float* __restrict__ in, const float* __restrict__ sumb,
    const float* __restrict__ inv, const float* __restrict__ Wl,
    const float* __restrict__ Wr, const float* __restrict__ bias,
    float* __restrict__ out, float* __restrict__ out2, int n) {
  constexpr int BM = 64;       // rows per block
  constexpr int KC = 64;       // k chunk
  constexpr int TM = 4;        // rows per thread
  constexpr int TN = DO / 16;  // cols per thread (8 for DO=128, 4 for DO=64)
  __shared__ __align__(16) float As[KC * (BM + 4)];
  __shared__ __align__(16) float Ws[KC * (DO + 4)];

  const int tx = threadIdx.x & 15;
  const int ty = threadIdx.x >> 4;
  const int row0 = blockIdx.x * BM;

  float acc[TM][TN];
#pragma unroll
  for (int r = 0; r < TM; ++r)
#pragma unroll
    for (int j = 0; j < TN; ++j) acc[r][j] = 0.f;

  const int nphase = AGG ? 2 : 1;
  for (int phase = 0; phase < nphase; ++phase) {
    const float* W = (phase == 0) ? Wr : Wl;
    const float* A = (phase == 0) ? in : sumb;
    const bool scale = AGG && (phase == 1);
    for (int k0 = 0; k0 < DI; k0 += KC) {
      // stage W chunk transposed: Ws[kk][col]
      for (int idx = threadIdx.x; idx < DO * (KC / 4); idx += 256) {
        int c = idx >> 4;  // KC/4 == 16
        int q = idx & 15;
        float4 v = *(const float4*)(W + (size_t)c * DI + k0 + q * 4);
        int kk = q * 4;
        Ws[(kk + 0) * (DO + 4) + c] = v.x;
        Ws[(kk + 1) * (DO + 4) + c] = v.y;
        Ws[(kk + 2) * (DO + 4) + c] = v.z;
        Ws[(kk + 3) * (DO + 4) + c] = v.w;
      }
      // stage A chunk transposed: As[kk][row] (mean-scale fused here)
      for (int idx = threadIdx.x; idx < BM * (KC / 4); idx += 256) {
        int r = idx >> 4;
        int q = idx & 15;
        int row = row0 + r;
        float4 v = make_float4(0.f, 0.f, 0.f, 0.f);
        if (row < n) {
          v = *(const float4*)(A + (size_t)row * DI + k0 + q * 4);
          if (scale) {
            float iv = inv[row];
            v.x *= iv; v.y *= iv; v.z *= iv; v.w *= iv;
          }
        }
        int kk = q * 4;
        As[(kk + 0) * (BM + 4) + r] = v.x;
        As[(kk + 1) * (BM + 4) + r] = v.y;
        As[(kk + 2) * (BM + 4) + r] = v.z;
        As[(kk + 3) * (BM + 4) + r] = v.w;
      }
      __syncthreads();
      const float* Ap = As + ty * TM;
      const float* Wp = Ws + tx * TN;
#pragma unroll 8
      for (int kk = 0; kk < KC; ++kk) {
        const float4 a = *(const float4*)(Ap + kk * (BM + 4));
        float av[TM] = {a.x, a.y, a.z, a.w};
        float wv[TN];
        const float4 w0 = *(const float4*)(Wp + kk * (DO + 4));
        wv[0] = w0.x; wv[1] = w0.y; wv[2] = w0.z; wv[3] = w0.w;
        if constexpr (TN == 8) {
          const float4 w1 = *(const float4*)(Wp + kk * (DO + 4) + 4);
          wv[4] = w1.x; wv[5] = w1.y; wv[6] = w1.z; wv[7] = w1.w;
        }
#pragma unroll
        for (int r = 0; r < TM; ++r)
#pragma unroll
          for (int j = 0; j < TN; ++j) acc[r][j] += av[r] * wv[j];
      }
      __syncthreads();
    }
  }

  // epilogue: bias + activation + store
#pragma unroll
  for (int r = 0; r < TM; ++r) {
    int row = row0 + ty * TM + r;
    if (row >= n) continue;
#pragma unroll
    for (int j = 0; j < TN; ++j) {
      float v = acc[r][j] + bias[tx * TN + j];
      if (ACT == ACT_TANH) v = tanhf(v);
      else if (ACT == ACT_LEAKY) v = (v > 0.f) ? v : 0.01f * v;
      out[(size_t)row * DO + tx * TN + j] = v;
      if (out2) out2[(size_t)row * DO + tx * TN + j] = v;
    }
  }
}

// dec4: SAGE 64 -> 3, scattered output layout (z2[:,:2] then z2[:,2])
__global__ __launch_bounds__(256) void dec4_kernel(
    const float* __restrict__ o, const float* __restrict__ sumb,
    const float* __restrict__ inv, const float* __restrict__ Wl,
    const float* __restrict__ bias, const float* __restrict__ Wr,
    float* __restrict__ out, int n) {
  __shared__ float wl[192], wr[192];
  for (int i = threadIdx.x; i < 192; i += 256) {
    wl[i] = Wl[i];
    wr[i] = Wr[i];
  }
  __syncthreads();
  int i = blockIdx.x * 256 + threadIdx.x;
  if (i >= n) return;
  float iv = inv[i];
  float a0 = bias[0], a1 = bias[1], a2 = bias[2];
  const float4* o4 = (const float4*)(o + (size_t)i * 64);
  const float4* s4 = (const float4*)(sumb + (size_t)i * 64);
#pragma unroll
  for (int q = 0; q < 16; ++q) {
    float4 ov = o4[q];
    float4 sv = s4[q];
    float m0 = sv.x * iv, m1 = sv.y * iv, m2 = sv.z * iv, m3 = sv.w * iv;
    int k = q * 4;
    a0 += m0 * wl[k] + m1 * wl[k + 1] + m2 * wl[k + 2] + m3 * wl[k + 3] +
          ov.x * wr[k] + ov.y * wr[k + 1] + ov.z * wr[k + 2] + ov.w * wr[k + 3];
    a1 += m0 * wl[64 + k] + m1 * wl[64 + k + 1] + m2 * wl[64 + k + 2] + m3 * wl[64 + k + 3] +
          ov.x * wr[64 + k] + ov.y * wr[64 + k + 1] + ov.z * wr[64 + k + 2] + ov.w * wr[64 + k + 3];
    a2 += m0 * wl[128 + k] + m1 * wl[128 + k + 1] + m2 * wl[128 + k + 2] + m3 * wl[128 + k + 3] +
          ov.x * wr[128 + k] + ov.y * wr[128 + k + 1] + ov.z * wr[128 + k + 2] + ov.w * wr[128 + k + 3];
  }
  out[2 * (size_t)i] = a0;
  out[2 * (size_t)i + 1] = a1;
  out[2 * (size_t)n + i] = a2;
}

extern "C" void kernel_launch(void* const* d_in, const int* in_sizes, int n_in,
                              void* d_out, int out_size, void* d_ws, size_t ws_size,
                              hipStream_t stream) {
  const float* x = (const float*)d_in[0];
  const int* ei = (const int*)d_in[1];
  const int N = in_sizes[0] / 64;
  const int E = in_sizes[1] / 2;
  const int* src = ei;
  const int* dst = ei + E;
  const float* g1Wl = (const float*)d_in[2];
  const float* g1b  = (const float*)d_in[3];
  const float* g1Wr = (const float*)d_in[4];
  const float* g2Wl = (const float*)d_in[5];
  const float* g2b  = (const float*)d_in[6];
  const float* g2Wr = (const float*)d_in[7];
  const float* g3Wl = (const float*)d_in[8];
  const float* g3b  = (const float*)d_in[9];
  const float* g3Wr = (const float*)d_in[10];
  const float* t2W  = (const float*)d_in[11];
  const float* t2b  = (const float*)d_in[12];
  const float* d1W  = (const float*)d_in[13];
  const float* d1b  = (const float*)d_in[14];
  const float* d2Wl = (const float*)d_in[15];
  const float* d2b  = (const float*)d_in[16];
  const float* d2Wr = (const float*)d_in[17];
  const float* d3Wl = (const float*)d_in[18];
  const float* d3b  = (const float*)d_in[19];
  const float* d3Wr = (const float*)d_in[20];
  const float* d4Wl = (const float*)d_in[21];
  const float* d4b  = (const float*)d_in[22];
  const float* d4Wr = (const float*)d_in[23];

  float* ws = (float*)d_ws;
  const size_t N128 = (size_t)N * 128;
  float* hA  = ws;                    // N x 128
  float* hB  = ws + N128;             // N x 128
  float* sum = ws + 2 * N128;         // N x 128
  int*   cnt = (int*)(ws + 3 * N128); // N ints
  float* inv = ws + 3 * N128 + N;     // N floats

  float* out = (float*)d_out;
  float* mu  = out + 3 * (size_t)N;       // N x 64
  float* lv  = mu + 64 * (size_t)N;       // N x 64 (logvar == mu)

  const int NB = (N + 63) / 64;

  // degrees (graph is fixed across layers)
  hipMemsetAsync(cnt, 0, (size_t)N * sizeof(int), stream);
  count_kernel<<<(E + 255) / 256, 256, 0, stream>>>(dst, cnt, E);
  inv_kernel<<<(N + 255) / 256, 256, 0, stream>>>(cnt, inv, N);

  // ggn1: x(64) -> hA(128), tanh
  hipMemsetAsync(sum, 0, (size_t)N * 64 * 4, stream);
  agg_kernel<64><<<(E * 16 + 255) / 256, 256, 0, stream>>>(x, src, dst, sum, E);
  node_kernel<64, 128, ACT_TANH, true><<<NB, 256, 0, stream>>>(
      x, sum, inv, g1Wl, g1Wr, g1b, hA, nullptr, N);

  // ggn2: hA -> hB, tanh
  hipMemsetAsync(sum, 0, (size_t)N * 128 * 4, stream);
  agg_kernel<128><<<(E * 32 + 255) / 256, 256, 0, stream>>>(hA, src, dst, sum, E);
  node_kernel<128, 128, ACT_TANH, true><<<NB, 256, 0, stream>>>(
      hA, sum, inv, g2Wl, g2Wr, g2b, hB, nullptr, N);

  // ggn3: hB -> hA, tanh
  hipMemsetAsync(sum, 0, (size_t)N * 128 * 4, stream);
  agg_kernel<128><<<(E * 32 + 255) / 256, 256, 0, stream>>>(hB, src, dst, sum, E);
  node_kernel<128, 128, ACT_TANH, true><<<NB, 256, 0, stream>>>(
      hB, sum, inv, g3Wl, g3Wr, g3b, hA, nullptr, N);

  // tr2: hA(128) -> mu(64) and logvar(64)
  node_kernel<128, 64, ACT_NONE, false><<<NB, 256, 0, stream>>>(
      hA, nullptr, nullptr, nullptr, t2W, t2b, mu, lv, N);

  // dec1: mu(64) -> hB(128), leaky
  node_kernel<64, 128, ACT_LEAKY, false><<<NB, 256, 0, stream>>>(
      mu, nullptr, nullptr, nullptr, d1W, d1b, hB, nullptr, N);

  // dec2: hB -> hA, leaky
  hipMemsetAsync(sum, 0, (size_t)N * 128 * 4, stream);
  agg_kernel<128><<<(E * 32 + 255) / 256, 256, 0, stream>>>(hB, src, dst, sum, E);
  node_kernel<128, 128, ACT_LEAKY, true><<<NB, 256, 0, stream>>>(
      hB, sum, inv, d2Wl, d2Wr, d2b, hA, nullptr, N);

  // dec3: hA(128) -> hB(64), tanh
  hipMemsetAsync(sum, 0, (size_t)N * 128 * 4, stream);
  agg_kernel<128><<<(E * 32 + 255) / 256, 256, 0, stream>>>(hA, src, dst, sum, E);
  node_kernel<128, 64, ACT_TANH, true><<<NB, 256, 0, stream>>>(
      hA, sum, inv, d3Wl, d3Wr, d3b, hB, nullptr, N);

  // dec4: hB(64) -> out (z2[:,:2], z2[:,2])
  hipMemsetAsync(sum, 0, (size_t)N * 64 * 4, stream);
  agg_kernel<64><<<(E * 16 + 255) / 256, 256, 0, stream>>>(hB, src, dst, sum, E);
  dec4_kernel<<<(N + 255) / 256, 256, 0, stream>>>(hB, sum, inv, d4Wl, d4b, d4Wr, out, N);
}

// Round 2
// 1916.019 us; speedup vs baseline: 7.5283x; 7.5283x over previous
//
#include <hip/hip_runtime.h>
#include <cmath>

// ---------------------------------------------------------------------------
// GCN_Message: graph VAE forward.
// Round 2: atomic scatter -> CSR gather.
//   - count degrees (int atomics), single-block wave-scan -> rowptr/cursor/inv
//   - fill: esrc sorted by dst via atomic cursor (order within segment
//     irrelevant for a sum)
//   - gather_mean: one wave per node, lanes cover feature row (float2 for
//     d=128), coalesced row reads, no atomics, writes mean directly
//   - node GEMM: 64-row tiles, W + A staged transposed in LDS, 4x8 reg tiles
// ---------------------------------------------------------------------------

constexpr int ACT_NONE = 0, ACT_TANH = 1, ACT_LEAKY = 2;

__global__ __launch_bounds__(256) void count_kernel(const int* __restrict__ dst,
                                                    int* __restrict__ cnt, int E) {
  int e = blockIdx.x * 256 + threadIdx.x;
  if (e < E) atomicAdd(&cnt[dst[e]], 1);
}

// single-workgroup exclusive scan over cnt -> rowptr, cursor; also inv = 1/max(cnt,1)
__global__ __launch_bounds__(1024) void scan_kernel(const int* __restrict__ cnt,
                                                    int* __restrict__ rowptr,
                                                    int* __restrict__ cursor,
                                                    float* __restrict__ inv, int n) {
  __shared__ int wsum[17];
  __shared__ int carry_s;
  const int lane = threadIdx.x & 63;
  const int wid = threadIdx.x >> 6;
  if (threadIdx.x == 0) carry_s = 0;
  __syncthreads();
  for (int base = 0; base < n; base += 1024) {
    int i = base + threadIdx.x;
    int v = (i < n) ? cnt[i] : 0;
    if (i < n) inv[i] = 1.0f / (float)(v > 1 ? v : 1);
    // inclusive scan within wave
    int x = v;
#pragma unroll
    for (int off = 1; off < 64; off <<= 1) {
      int t = __shfl_up(x, off);
      if (lane >= off) x += t;
    }
    if (lane == 63) wsum[wid + 1] = x;
    __syncthreads();
    if (threadIdx.x == 0) {
      wsum[0] = carry_s;
      for (int w = 1; w <= 16; ++w) wsum[w] += wsum[w - 1];
      carry_s = wsum[16];
    }
    __syncthreads();
    int excl = wsum[wid] + x - v;
    if (i < n) {
      rowptr[i] = excl;
      cursor[i] = excl;
    }
    __syncthreads();
  }
  if (threadIdx.x == 0) rowptr[n] = carry_s;
}

__global__ __launch_bounds__(256) void fill_kernel(const int* __restrict__ src,
                                                   const int* __restrict__ dst,
                                                   int* __restrict__ cursor,
                                                   int* __restrict__ esrc, int E) {
  int e = blockIdx.x * 256 + threadIdx.x;
  if (e < E) {
    int p = atomicAdd(&cursor[dst[e]], 1);
    esrc[p] = src[e];
  }
}

// one wave per node: mean over neighbor rows. D=128: lane holds float2.
template <int D>
__global__ __launch_bounds__(256) void gather_mean_kernel(
    const float* __restrict__ in, const int* __restrict__ esrc,
    const int* __restrict__ rowptr, const float* __restrict__ inv,
    float* __restrict__ meanb, int n) {
  const int node = blockIdx.x * 4 + (threadIdx.x >> 6);
  const int lane = threadIdx.x & 63;
  if (node >= n) return;
  const int beg = rowptr[node];
  const int end = rowptr[node + 1];
  const float iv = inv[node];
  if constexpr (D == 128) {
    const float2* base = (const float2*)in;
    float ax = 0.f, ay = 0.f, bx = 0.f, by = 0.f;
    int j = beg;
    for (; j + 1 < end; j += 2) {
      int s0 = esrc[j];
      int s1 = esrc[j + 1];
      float2 v0 = base[(size_t)s0 * 64 + lane];
      float2 v1 = base[(size_t)s1 * 64 + lane];
      ax += v0.x; ay += v0.y;
      bx += v1.x; by += v1.y;
    }
    if (j < end) {
      int s0 = esrc[j];
      float2 v0 = base[(size_t)s0 * 64 + lane];
      ax += v0.x; ay += v0.y;
    }
    float2 r;
    r.x = (ax + bx) * iv;
    r.y = (ay + by) * iv;
    ((float2*)meanb)[(size_t)node * 64 + lane] = r;
  } else {
    float a = 0.f, b = 0.f;
    int j = beg;
    for (; j + 1 < end; j += 2) {
      int s0 = esrc[j];
      int s1 = esrc[j + 1];
      a += in[(size_t)s0 * 64 + lane];
      b += in[(size_t)s1 * 64 + lane];
    }
    if (j < end) a += in[(size_t)esrc[j] * 64 + lane];
    meanb[(size_t)node * 64 + lane] = (a + b) * iv;
  }
}

// out[row, col] = act( (AGG ? mean@Wl^T : 0) + in@Wr^T + b ), 64-row blocks.
// LDS holds transposed chunks: As[kk][row], Ws[kk][col]; thread tile 4 rows x TN cols.
template <int DI, int DO, int ACT, bool AGG>
__global__ __launch_bounds__(256) void node_kernel(
    const float* __restrict__ in, const float* __restrict__ meanb,
    const float* __restrict__ Wl, const float* __restrict__ Wr,
    const float* __restrict__ bias, float* __restrict__ out,
    float* __restrict__ out2, int n) {
  constexpr int BM = 64;       // rows per block
  constexpr int KC = 64;       // k chunk
  constexpr int TM = 4;        // rows per thread
  constexpr int TN = DO / 16;  // cols per thread (8 for DO=128, 4 for DO=64)
  __shared__ __align__(16) float As[KC * (BM + 4)];
  __shared__ __align__(16) float Ws[KC * (DO + 4)];

  const int tx = threadIdx.x & 15;
  const int ty = threadIdx.x >> 4;
  const int row0 = blockIdx.x * BM;

  float acc[TM][TN];
#pragma unroll
  for (int r = 0; r < TM; ++r)
#pragma unroll
    for (int j = 0; j < TN; ++j) acc[r][j] = 0.f;

  const int nphase = AGG ? 2 : 1;
  for (int phase = 0; phase < nphase; ++phase) {
    const float* W = (phase == 0) ? Wr : Wl;
    const float* A = (phase == 0) ? in : meanb;
    for (int k0 = 0; k0 < DI; k0 += KC) {
      // stage W chunk transposed: Ws[kk][col]
      for (int idx = threadIdx.x; idx < DO * (KC / 4); idx += 256) {
        int c = idx >> 4;  // KC/4 == 16
        int q = idx & 15;
        float4 v = *(const float4*)(W + (size_t)c * DI + k0 + q * 4);
        int kk = q * 4;
        Ws[(kk + 0) * (DO + 4) + c] = v.x;
        Ws[(kk + 1) * (DO + 4) + c] = v.y;
        Ws[(kk + 2) * (DO + 4) + c] = v.z;
        Ws[(kk + 3) * (DO + 4) + c] = v.w;
      }
      // stage A chunk transposed: As[kk][row]
      for (int idx = threadIdx.x; idx < BM * (KC / 4); idx += 256) {
        int r = idx >> 4;
        int q = idx & 15;
        int row = row0 + r;
        float4 v = make_float4(0.f, 0.f, 0.f, 0.f);
        if (row < n) v = *(const float4*)(A + (size_t)row * DI + k0 + q * 4);
        int kk = q * 4;
        As[(kk + 0) * (BM + 4) + r] = v.x;
        As[(kk + 1) * (BM + 4) + r] = v.y;
        As[(kk + 2) * (BM + 4) + r] = v.z;
        As[(kk + 3) * (BM + 4) + r] = v.w;
      }
      __syncthreads();
      const float* Ap = As + ty * TM;
      const float* Wp = Ws + tx * TN;
#pragma unroll 8
      for (int kk = 0; kk < KC; ++kk) {
        const float4 a = *(const float4*)(Ap + kk * (BM + 4));
        float av[TM] = {a.x, a.y, a.z, a.w};
        float wv[TN];
        const float4 w0 = *(const float4*)(Wp + kk * (DO + 4));
        wv[0] = w0.x; wv[1] = w0.y; wv[2] = w0.z; wv[3] = w0.w;
        if constexpr (TN == 8) {
          const float4 w1 = *(const float4*)(Wp + kk * (DO + 4) + 4);
          wv[4] = w1.x; wv[5] = w1.y; wv[6] = w1.z; wv[7] = w1.w;
        }
#pragma unroll
        for (int r = 0; r < TM; ++r)
#pragma unroll
          for (int j = 0; j < TN; ++j) acc[r][j] += av[r] * wv[j];
      }
      __syncthreads();
    }
  }

  // epilogue: bias + activation + store
#pragma unroll
  for (int r = 0; r < TM; ++r) {
    int row = row0 + ty * TM + r;
    if (row >= n) continue;
#pragma unroll
    for (int j = 0; j < TN; ++j) {
      float v = acc[r][j] + bias[tx * TN + j];
      if (ACT == ACT_TANH) v = tanhf(v);
      else if (ACT == ACT_LEAKY) v = (v > 0.f) ? v : 0.01f * v;
      out[(size_t)row * DO + tx * TN + j] = v;
      if (out2) out2[(size_t)row * DO + tx * TN + j] = v;
    }
  }
}

// dec4: SAGE 64 -> 3, scattered output layout (z2[:,:2] then z2[:,2])
__global__ __launch_bounds__(256) void dec4_kernel(
    const float* __restrict__ o, const float* __restrict__ meanb,
    const float* __restrict__ Wl, const float* __restrict__ bias,
    const float* __restrict__ Wr, float* __restrict__ out, int n) {
  __shared__ float wl[192], wr[192];
  for (int i = threadIdx.x; i < 192; i += 256) {
    wl[i] = Wl[i];
    wr[i] = Wr[i];
  }
  __syncthreads();
  int i = blockIdx.x * 256 + threadIdx.x;
  if (i >= n) return;
  float a0 = bias[0], a1 = bias[1], a2 = bias[2];
  const float4* o4 = (const float4*)(o + (size_t)i * 64);
  const float4* s4 = (const float4*)(meanb + (size_t)i * 64);
#pragma unroll
  for (int q = 0; q < 16; ++q) {
    float4 ov = o4[q];
    float4 sv = s4[q];
    int k = q * 4;
    a0 += sv.x * wl[k] + sv.y * wl[k + 1] + sv.z * wl[k + 2] + sv.w * wl[k + 3] +
          ov.x * wr[k] + ov.y * wr[k + 1] + ov.z * wr[k + 2] + ov.w * wr[k + 3];
    a1 += sv.x * wl[64 + k] + sv.y * wl[64 + k + 1] + sv.z * wl[64 + k + 2] + sv.w * wl[64 + k + 3] +
          ov.x * wr[64 + k] + ov.y * wr[64 + k + 1] + ov.z * wr[64 + k + 2] + ov.w * wr[64 + k + 3];
    a2 += sv.x * wl[128 + k] + sv.y * wl[128 + k + 1] + sv.z * wl[128 + k + 2] + sv.w * wl[128 + k + 3] +
          ov.x * wr[128 + k] + ov.y * wr[128 + k + 1] + ov.z * wr[128 + k + 2] + ov.w * wr[128 + k + 3];
  }
  out[2 * (size_t)i] = a0;
  out[2 * (size_t)i + 1] = a1;
  out[2 * (size_t)n + i] = a2;
}

extern "C" void kernel_launch(void* const* d_in, const int* in_sizes, int n_in,
                              void* d_out, int out_size, void* d_ws, size_t ws_size,
                              hipStream_t stream) {
  const float* x = (const float*)d_in[0];
  const int* ei = (const int*)d_in[1];
  const int N = in_sizes[0] / 64;
  const int E = in_sizes[1] / 2;
  const int* src = ei;
  const int* dst = ei + E;
  const float* g1Wl = (const float*)d_in[2];
  const float* g1b  = (const float*)d_in[3];
  const float* g1Wr = (const float*)d_in[4];
  const float* g2Wl = (const float*)d_in[5];
  const float* g2b  = (const float*)d_in[6];
  const float* g2Wr = (const float*)d_in[7];
  const float* g3Wl = (const float*)d_in[8];
  const float* g3b  = (const float*)d_in[9];
  const float* g3Wr = (const float*)d_in[10];
  const float* t2W  = (const float*)d_in[11];
  const float* t2b  = (const float*)d_in[12];
  const float* d1W  = (const float*)d_in[13];
  const float* d1b  = (const float*)d_in[14];
  const float* d2Wl = (const float*)d_in[15];
  const float* d2b  = (const float*)d_in[16];
  const float* d2Wr = (const float*)d_in[17];
  const float* d3Wl = (const float*)d_in[18];
  const float* d3b  = (const float*)d_in[19];
  const float* d3Wr = (const float*)d_in[20];
  const float* d4Wl = (const float*)d_in[21];
  const float* d4b  = (const float*)d_in[22];
  const float* d4Wr = (const float*)d_in[23];

  float* ws = (float*)d_ws;
  const size_t N128 = (size_t)N * 128;
  float* hA   = ws;                        // N x 128
  float* hB   = ws + N128;                 // N x 128
  float* mean = ws + 2 * N128;             // N x 128
  int*   cnt  = (int*)(ws + 3 * N128);     // N
  float* inv  = ws + 3 * N128 + N;         // N
  int*   rowp = (int*)(ws + 3 * N128 + 2 * (size_t)N);      // N+1
  int*   curs = (int*)(ws + 3 * N128 + 3 * (size_t)N + 1);  // N
  int*   esrc = (int*)(ws + 3 * N128 + 4 * (size_t)N + 2);  // E

  float* out = (float*)d_out;
  float* mu  = out + 3 * (size_t)N;  // N x 64
  float* lv  = mu + 64 * (size_t)N;  // N x 64 (logvar == mu)

  const int NB = (N + 63) / 64;
  const int GB = (N + 3) / 4;  // gather: 4 waves (nodes) per block

  // --- CSR build (once per call; graph fixed across layers) ---
  hipMemsetAsync(cnt, 0, (size_t)N * sizeof(int), stream);
  count_kernel<<<(E + 255) / 256, 256, 0, stream>>>(dst, cnt, E);
  scan_kernel<<<1, 1024, 0, stream>>>(cnt, rowp, curs, inv, N);
  fill_kernel<<<(E + 255) / 256, 256, 0, stream>>>(src, dst, curs, esrc, E);

  // ggn1: x(64) -> hA(128), tanh
  gather_mean_kernel<64><<<GB, 256, 0, stream>>>(x, esrc, rowp, inv, mean, N);
  node_kernel<64, 128, ACT_TANH, true><<<NB, 256, 0, stream>>>(
      x, mean, g1Wl, g1Wr, g1b, hA, nullptr, N);

  // ggn2: hA -> hB, tanh
  gather_mean_kernel<128><<<GB, 256, 0, stream>>>(hA, esrc, rowp, inv, mean, N);
  node_kernel<128, 128, ACT_TANH, true><<<NB, 256, 0, stream>>>(
      hA, mean, g2Wl, g2Wr, g2b, hB, nullptr, N);

  // ggn3: hB -> hA, tanh
  gather_mean_kernel<128><<<GB, 256, 0, stream>>>(hB, esrc, rowp, inv, mean, N);
  node_kernel<128, 128, ACT_TANH, true><<<NB, 256, 0, stream>>>(
      hB, mean, g3Wl, g3Wr, g3b, hA, nullptr, N);

  // tr2: hA(128) -> mu(64) and logvar(64)
  node_kernel<128, 64, ACT_NONE, false><<<NB, 256, 0, stream>>>(
      hA, nullptr, nullptr, t2W, t2b, mu, lv, N);

  // dec1: mu(64) -> hB(128), leaky
  node_kernel<64, 128, ACT_LEAKY, false><<<NB, 256, 0, stream>>>(
      mu, nullptr, nullptr, d1W, d1b, hB, nullptr, N);

  // dec2: hB -> hA, leaky
  gather_mean_kernel<128><<<GB, 256, 0, stream>>>(hB, esrc, rowp, inv, mean, N);
  node_kernel<128, 128, ACT_LEAKY, true><<<NB, 256, 0, stream>>>(
      hB, mean, d2Wl, d2Wr, d2b, hA, nullptr, N);

  // dec3: hA(128) -> hB(64), tanh
  gather_mean_kernel<128><<<GB, 256, 0, stream>>>(hA, esrc, rowp, inv, mean, N);
  node_kernel<128, 64, ACT_TANH, true><<<NB, 256, 0, stream>>>(
      hA, mean, d3Wl, d3Wr, d3b, hB, nullptr, N);

  // dec4: hB(64) -> out (z2[:,:2], z2[:,2])
  gather_mean_kernel<64><<<GB, 256, 0, stream>>>(hB, esrc, rowp, inv, mean, N);
  dec4_kernel<<<(N + 255) / 256, 256, 0, stream>>>(hB, mean, d4Wl, d4b, d4Wr, out, N);
}

// Round 3
// 1675.315 us; speedup vs baseline: 8.6099x; 1.1437x over previous
//
#include <hip/hip_runtime.h>
#include <cmath>

// ---------------------------------------------------------------------------
// GCN_Message: graph VAE forward. Round 3:
//   - node_kernel: W-column remap {tx*4, 64+tx*4} -> conflict-free b128 LDS
//     reads (was 4-way on tx*8); float4 epilogue stores
//   - linearity of mean: dec3/dec4 apply Wl BEFORE gathering (gather 64-d /
//     4-d instead of 128-d / 64-d)
//   - CSR gather (R2), 64-row-tile fp32 GEMM with LDS staging
// ---------------------------------------------------------------------------

constexpr int ACT_NONE = 0, ACT_TANH = 1, ACT_LEAKY = 2;

__global__ __launch_bounds__(256) void count_kernel(const int* __restrict__ dst,
                                                    int* __restrict__ cnt, int E) {
  int e = blockIdx.x * 256 + threadIdx.x;
  if (e < E) atomicAdd(&cnt[dst[e]], 1);
}

// single-workgroup exclusive scan over cnt -> rowptr, cursor; also inv = 1/max(cnt,1)
__global__ __launch_bounds__(1024) void scan_kernel(const int* __restrict__ cnt,
                                                    int* __restrict__ rowptr,
                                                    int* __restrict__ cursor,
                                                    float* __restrict__ inv, int n) {
  __shared__ int wsum[17];
  __shared__ int carry_s;
  const int lane = threadIdx.x & 63;
  const int wid = threadIdx.x >> 6;
  if (threadIdx.x == 0) carry_s = 0;
  __syncthreads();
  for (int base = 0; base < n; base += 1024) {
    int i = base + threadIdx.x;
    int v = (i < n) ? cnt[i] : 0;
    if (i < n) inv[i] = 1.0f / (float)(v > 1 ? v : 1);
    int x = v;
#pragma unroll
    for (int off = 1; off < 64; off <<= 1) {
      int t = __shfl_up(x, off);
      if (lane >= off) x += t;
    }
    if (lane == 63) wsum[wid + 1] = x;
    __syncthreads();
    if (threadIdx.x == 0) {
      wsum[0] = carry_s;
      for (int w = 1; w <= 16; ++w) wsum[w] += wsum[w - 1];
      carry_s = wsum[16];
    }
    __syncthreads();
    int excl = wsum[wid] + x - v;
    if (i < n) {
      rowptr[i] = excl;
      cursor[i] = excl;
    }
    __syncthreads();
  }
  if (threadIdx.x == 0) rowptr[n] = carry_s;
}

__global__ __launch_bounds__(256) void fill_kernel(const int* __restrict__ src,
                                                   const int* __restrict__ dst,
                                                   int* __restrict__ cursor,
                                                   int* __restrict__ esrc, int E) {
  int e = blockIdx.x * 256 + threadIdx.x;
  if (e < E) {
    int p = atomicAdd(&cursor[dst[e]], 1);
    esrc[p] = src[e];
  }
}

// one wave per node: mean over neighbor rows. D=128: lane holds float2.
template <int D>
__global__ __launch_bounds__(256) void gather_mean_kernel(
    const float* __restrict__ in, const int* __restrict__ esrc,
    const int* __restrict__ rowptr, const float* __restrict__ inv,
    float* __restrict__ meanb, int n) {
  const int node = blockIdx.x * 4 + (threadIdx.x >> 6);
  const int lane = threadIdx.x & 63;
  if (node >= n) return;
  const int beg = rowptr[node];
  const int end = rowptr[node + 1];
  const float iv = inv[node];
  if constexpr (D == 128) {
    const float2* base = (const float2*)in;
    float ax = 0.f, ay = 0.f, bx = 0.f, by = 0.f;
    int j = beg;
    for (; j + 1 < end; j += 2) {
      int s0 = esrc[j];
      int s1 = esrc[j + 1];
      float2 v0 = base[(size_t)s0 * 64 + lane];
      float2 v1 = base[(size_t)s1 * 64 + lane];
      ax += v0.x; ay += v0.y;
      bx += v1.x; by += v1.y;
    }
    if (j < end) {
      int s0 = esrc[j];
      float2 v0 = base[(size_t)s0 * 64 + lane];
      ax += v0.x; ay += v0.y;
    }
    float2 r;
    r.x = (ax + bx) * iv;
    r.y = (ay + by) * iv;
    ((float2*)meanb)[(size_t)node * 64 + lane] = r;
  } else {
    float a = 0.f, b = 0.f;
    int j = beg;
    for (; j + 1 < end; j += 2) {
      int s0 = esrc[j];
      int s1 = esrc[j + 1];
      a += in[(size_t)s0 * 64 + lane];
      b += in[(size_t)s1 * 64 + lane];
    }
    if (j < end) a += in[(size_t)esrc[j] * 64 + lane];
    meanb[(size_t)node * 64 + lane] = (a + b) * iv;
  }
}

// thread per node: mean over 4-wide (padded float4) rows
__global__ __launch_bounds__(256) void gather_mean4_kernel(
    const float* __restrict__ y4, const int* __restrict__ esrc,
    const int* __restrict__ rowptr, const float* __restrict__ inv,
    float* __restrict__ mean4, int n) {
  int i = blockIdx.x * 256 + threadIdx.x;
  if (i >= n) return;
  const int beg = rowptr[i], end = rowptr[i + 1];
  const float iv = inv[i];
  float sx = 0.f, sy = 0.f, sz = 0.f;
  const float4* b = (const float4*)y4;
  for (int j = beg; j < end; ++j) {
    float4 v = b[esrc[j]];
    sx += v.x; sy += v.y; sz += v.z;
  }
  float4 r = make_float4(sx * iv, sy * iv, sz * iv, 0.f);
  ((float4*)mean4)[i] = r;
}

// out[row, col] = act( (AGG ? mean@Wl^T : 0) + (ADDMEAN ? mean : 0)
//                      + in@Wr^T + (BIAS ? b : 0) ), 64-row blocks.
// thread (tx,ty): rows ty*4.., cols {tx*4..+3} and (DO=128) {64+tx*4..+3}
template <int DI, int DO, int ACT, bool AGG, bool ADDMEAN, bool BIAS>
__global__ __launch_bounds__(256) void node_kernel(
    const float* __restrict__ in, const float* __restrict__ meanb,
    const float* __restrict__ Wl, const float* __restrict__ Wr,
    const float* __restrict__ bias, float* __restrict__ out,
    float* __restrict__ out2, int n) {
  constexpr int BM = 64;
  constexpr int KC = 64;
  constexpr int TM = 4;
  constexpr int TN = DO / 16;   // 8 for DO=128, 4 for DO=64
  constexpr int NU = TN / 4;    // float4 groups per thread (2 or 1)
  __shared__ __align__(16) float As[KC * (BM + 4)];
  __shared__ __align__(16) float Ws[KC * (DO + 4)];

  const int tx = threadIdx.x & 15;
  const int ty = threadIdx.x >> 4;
  const int row0 = blockIdx.x * BM;

  float acc[TM][TN];
#pragma unroll
  for (int r = 0; r < TM; ++r)
#pragma unroll
    for (int j = 0; j < TN; ++j) acc[r][j] = 0.f;

  const int nphase = AGG ? 2 : 1;
  for (int phase = 0; phase < nphase; ++phase) {
    const float* W = (phase == 0) ? Wr : Wl;
    const float* A = (phase == 0) ? in : meanb;
    for (int k0 = 0; k0 < DI; k0 += KC) {
      // stage W chunk transposed: Ws[kk][col], stride DO+4
      for (int idx = threadIdx.x; idx < DO * (KC / 4); idx += 256) {
        int c = idx >> 4;
        int q = idx & 15;
        float4 v = *(const float4*)(W + (size_t)c * DI + k0 + q * 4);
        int kk = q * 4;
        Ws[(kk + 0) * (DO + 4) + c] = v.x;
        Ws[(kk + 1) * (DO + 4) + c] = v.y;
        Ws[(kk + 2) * (DO + 4) + c] = v.z;
        Ws[(kk + 3) * (DO + 4) + c] = v.w;
      }
      // stage A chunk transposed: As[kk][row], stride BM+4
      for (int idx = threadIdx.x; idx < BM * (KC / 4); idx += 256) {
        int r = idx >> 4;
        int q = idx & 15;
        int row = row0 + r;
        float4 v = make_float4(0.f, 0.f, 0.f, 0.f);
        if (row < n) v = *(const float4*)(A + (size_t)row * DI + k0 + q * 4);
        int kk = q * 4;
        As[(kk + 0) * (BM + 4) + r] = v.x;
        As[(kk + 1) * (BM + 4) + r] = v.y;
        As[(kk + 2) * (BM + 4) + r] = v.z;
        As[(kk + 3) * (BM + 4) + r] = v.w;
      }
      __syncthreads();
      const float* Ap = As + ty * TM;
      const float* Wp = Ws + tx * 4;
#pragma unroll 8
      for (int kk = 0; kk < KC; ++kk) {
        const float4 a = *(const float4*)(Ap + kk * (BM + 4));
        float av[TM] = {a.x, a.y, a.z, a.w};
        float wv[TN];
        const float4 w0 = *(const float4*)(Wp + kk * (DO + 4));
        wv[0] = w0.x; wv[1] = w0.y; wv[2] = w0.z; wv[3] = w0.w;
        if constexpr (NU == 2) {
          const float4 w1 = *(const float4*)(Wp + kk * (DO + 4) + 64);
          wv[4] = w1.x; wv[5] = w1.y; wv[6] = w1.z; wv[7] = w1.w;
        }
#pragma unroll
        for (int r = 0; r < TM; ++r)
#pragma unroll
          for (int j = 0; j < TN; ++j) acc[r][j] += av[r] * wv[j];
      }
      __syncthreads();
    }
  }

  // epilogue: bias + mean-add + activation + float4 stores
#pragma unroll
  for (int r = 0; r < TM; ++r) {
    int row = row0 + ty * TM + r;
    if (row >= n) continue;
#pragma unroll
    for (int u = 0; u < NU; ++u) {
      const int col = u * 64 + tx * 4;
      float v[4];
#pragma unroll
      for (int j = 0; j < 4; ++j) {
        float t = acc[r][u * 4 + j];
        if (BIAS) t += bias[col + j];
        if (ADDMEAN) t += meanb[(size_t)row * DO + col + j];
        if (ACT == ACT_TANH) t = tanhf(t);
        else if (ACT == ACT_LEAKY) t = (t > 0.f) ? t : 0.01f * t;
        v[j] = t;
      }
      float4 q = make_float4(v[0], v[1], v[2], v[3]);
      *(float4*)(out + (size_t)row * DO + col) = q;
      if (out2) *(float4*)(out2 + (size_t)row * DO + col) = q;
    }
  }
}

// y4[node] = hB[node] @ Wl^T (3 outputs, padded float4); wave per node
__global__ __launch_bounds__(256) void dec4_pre_kernel(
    const float* __restrict__ hB, const float* __restrict__ Wl,
    float* __restrict__ y4, int n) {
  const int node = blockIdx.x * 4 + (threadIdx.x >> 6);
  const int lane = threadIdx.x & 63;
  if (node >= n) return;
  float v = hB[(size_t)node * 64 + lane];
  float p0 = v * Wl[lane];
  float p1 = v * Wl[64 + lane];
  float p2 = v * Wl[128 + lane];
#pragma unroll
  for (int off = 32; off >= 1; off >>= 1) {
    p0 += __shfl_xor(p0, off);
    p1 += __shfl_xor(p1, off);
    p2 += __shfl_xor(p2, off);
  }
  if (lane == 0) ((float4*)y4)[node] = make_float4(p0, p1, p2, 0.f);
}

// out = mean4 + b + hB@Wr^T, scattered layout (z2[:,:2], z2[:,2]); wave/node
__global__ __launch_bounds__(256) void dec4_final_kernel(
    const float* __restrict__ hB, const float* __restrict__ mean4,
    const float* __restrict__ Wr, const float* __restrict__ bias,
    float* __restrict__ out, int n) {
  const int node = blockIdx.x * 4 + (threadIdx.x >> 6);
  const int lane = threadIdx.x & 63;
  if (node >= n) return;
  float v = hB[(size_t)node * 64 + lane];
  float p0 = v * Wr[lane];
  float p1 = v * Wr[64 + lane];
  float p2 = v * Wr[128 + lane];
#pragma unroll
  for (int off = 32; off >= 1; off >>= 1) {
    p0 += __shfl_xor(p0, off);
    p1 += __shfl_xor(p1, off);
    p2 += __shfl_xor(p2, off);
  }
  if (lane == 0) {
    float4 m = ((const float4*)mean4)[node];
    out[2 * (size_t)node]     = p0 + m.x + bias[0];
    out[2 * (size_t)node + 1] = p1 + m.y + bias[1];
    out[2 * (size_t)node + (size_t)0 + 0] = out[2 * (size_t)node];  // no-op keep
    out[2 * (size_t)n + node] = p2 + m.z + bias[2];
  }
}

extern "C" void kernel_launch(void* const* d_in, const int* in_sizes, int n_in,
                              void* d_out, int out_size, void* d_ws, size_t ws_size,
                              hipStream_t stream) {
  const float* x = (const float*)d_in[0];
  const int* ei = (const int*)d_in[1];
  const int N = in_sizes[0] / 64;
  const int E = in_sizes[1] / 2;
  const int* src = ei;
  const int* dst = ei + E;
  const float* g1Wl = (const float*)d_in[2];
  const float* g1b  = (const float*)d_in[3];
  const float* g1Wr = (const float*)d_in[4];
  const float* g2Wl = (const float*)d_in[5];
  const float* g2b  = (const float*)d_in[6];
  const float* g2Wr = (const float*)d_in[7];
  const float* g3Wl = (const float*)d_in[8];
  const float* g3b  = (const float*)d_in[9];
  const float* g3Wr = (const float*)d_in[10];
  const float* t2W  = (const float*)d_in[11];
  const float* t2b  = (const float*)d_in[12];
  const float* d1W  = (const float*)d_in[13];
  const float* d1b  = (const float*)d_in[14];
  const float* d2Wl = (const float*)d_in[15];
  const float* d2b  = (const float*)d_in[16];
  const float* d2Wr = (const float*)d_in[17];
  const float* d3Wl = (const float*)d_in[18];
  const float* d3b  = (const float*)d_in[19];
  const float* d3Wr = (const float*)d_in[20];
  const float* d4Wl = (const float*)d_in[21];
  const float* d4b  = (const float*)d_in[22];
  const float* d4Wr = (const float*)d_in[23];

  float* ws = (float*)d_ws;
  const size_t N128 = (size_t)N * 128;
  float* hA   = ws;                        // N x 128
  float* hB   = ws + N128;                 // N x 128
  float* mean = ws + 2 * N128;             // N x 128 (also hosts y3/mean3, y4/mean4)
  int*   cnt  = (int*)(ws + 3 * N128);     // N
  float* inv  = ws + 3 * N128 + N;         // N
  int*   rowp = (int*)(ws + 3 * N128 + 2 * (size_t)N);      // N+1
  int*   curs = (int*)(ws + 3 * N128 + 3 * (size_t)N + 1);  // N
  int*   esrc = (int*)(ws + 3 * N128 + 4 * (size_t)N + 2);  // E

  float* y3    = mean;                   // N x 64
  float* mean3 = mean + (size_t)N * 64;  // N x 64
  float* y4    = mean;                   // N x 4
  float* mean4 = mean + (size_t)N * 4;   // N x 4

  float* out = (float*)d_out;
  float* mu  = out + 3 * (size_t)N;  // N x 64
  float* lv  = mu + 64 * (size_t)N;  // N x 64 (logvar == mu)

  const int NB = (N + 63) / 64;
  const int GB = (N + 3) / 4;

  // --- CSR build ---
  hipMemsetAsync(cnt, 0, (size_t)N * sizeof(int), stream);
  count_kernel<<<(E + 255) / 256, 256, 0, stream>>>(dst, cnt, E);
  scan_kernel<<<1, 1024, 0, stream>>>(cnt, rowp, curs, inv, N);
  fill_kernel<<<(E + 255) / 256, 256, 0, stream>>>(src, dst, curs, esrc, E);

  // ggn1: x(64) -> hA(128), tanh
  gather_mean_kernel<64><<<GB, 256, 0, stream>>>(x, esrc, rowp, inv, mean, N);
  node_kernel<64, 128, ACT_TANH, true, false, true><<<NB, 256, 0, stream>>>(
      x, mean, g1Wl, g1Wr, g1b, hA, nullptr, N);

  // ggn2: hA -> hB, tanh
  gather_mean_kernel<128><<<GB, 256, 0, stream>>>(hA, esrc, rowp, inv, mean, N);
  node_kernel<128, 128, ACT_TANH, true, false, true><<<NB, 256, 0, stream>>>(
      hA, mean, g2Wl, g2Wr, g2b, hB, nullptr, N);

  // ggn3: hB -> hA, tanh
  gather_mean_kernel<128><<<GB, 256, 0, stream>>>(hB, esrc, rowp, inv, mean, N);
  node_kernel<128, 128, ACT_TANH, true, false, true><<<NB, 256, 0, stream>>>(
      hB, mean, g3Wl, g3Wr, g3b, hA, nullptr, N);

  // tr2: hA(128) -> mu(64) and logvar(64)
  node_kernel<128, 64, ACT_NONE, false, false, true><<<NB, 256, 0, stream>>>(
      hA, nullptr, nullptr, t2W, t2b, mu, lv, N);

  // dec1: mu(64) -> hB(128), leaky
  node_kernel<64, 128, ACT_LEAKY, false, false, true><<<NB, 256, 0, stream>>>(
      mu, nullptr, nullptr, d1W, d1b, hB, nullptr, N);

  // dec2: hB -> hA, leaky
  gather_mean_kernel<128><<<GB, 256, 0, stream>>>(hB, esrc, rowp, inv, mean, N);
  node_kernel<128, 128, ACT_LEAKY, true, false, true><<<NB, 256, 0, stream>>>(
      hB, mean, d2Wl, d2Wr, d2b, hA, nullptr, N);

  // dec3 (linearity): y3 = hA@Wl^T; gather y3 -> mean3; hB = tanh(mean3 + hA@Wr + b)
  node_kernel<128, 64, ACT_NONE, false, false, false><<<NB, 256, 0, stream>>>(
      hA, nullptr, nullptr, d3Wl, nullptr, y3, nullptr, N);
  gather_mean_kernel<64><<<GB, 256, 0, stream>>>(y3, esrc, rowp, inv, mean3, N);
  node_kernel<128, 64, ACT_TANH, false, true, true><<<NB, 256, 0, stream>>>(
      hA, mean3, nullptr, d3Wr, d3b, hB, nullptr, N);

  // dec4 (linearity): y4 = hB@Wl^T (3-pad-4); gather4; out = mean4 + b + hB@Wr
  dec4_pre_kernel<<<GB, 256, 0, stream>>>(hB, d4Wl, y4, N);
  gather_mean4_kernel<<<(N + 255) / 256, 256, 0, stream>>>(y4, esrc, rowp, inv, mean4, N);
  dec4_final_kernel<<<GB, 256, 0, stream>>>(hB, mean4, d4Wr, d4b, out, N);
}

// Round 4
// 1591.402 us; speedup vs baseline: 9.0639x; 1.0527x over previous
//
#include <hip/hip_runtime.h>
#include <cmath>

// ---------------------------------------------------------------------------
// GCN_Message: graph VAE forward. Round 4:
//   - node_kernel v2: 128x{128,64} block tile, 8x{8,4} thread tile, KC=32,
//     XOR-swizzled LDS (conflict-free staging writes AND reads, no padding),
//     __launch_bounds__(256,4) -> 4 blocks/CU
//   - gather v2: batch-load 64 neighbor indices, __shfl broadcast, 4 rows in
//     flight per wave
//   - linearity of mean for dec3/dec4 (gather in output space)
// ---------------------------------------------------------------------------

constexpr int ACT_NONE = 0, ACT_TANH = 1, ACT_LEAKY = 2;

__global__ __launch_bounds__(256) void count_kernel(const int* __restrict__ dst,
                                                    int* __restrict__ cnt, int E) {
  int e = blockIdx.x * 256 + threadIdx.x;
  if (e < E) atomicAdd(&cnt[dst[e]], 1);
}

// single-workgroup exclusive scan over cnt -> rowptr, cursor; also inv = 1/max(cnt,1)
__global__ __launch_bounds__(1024) void scan_kernel(const int* __restrict__ cnt,
                                                    int* __restrict__ rowptr,
                                                    int* __restrict__ cursor,
                                                    float* __restrict__ inv, int n) {
  __shared__ int wsum[17];
  __shared__ int carry_s;
  const int lane = threadIdx.x & 63;
  const int wid = threadIdx.x >> 6;
  if (threadIdx.x == 0) carry_s = 0;
  __syncthreads();
  for (int base = 0; base < n; base += 1024) {
    int i = base + threadIdx.x;
    int v = (i < n) ? cnt[i] : 0;
    if (i < n) inv[i] = 1.0f / (float)(v > 1 ? v : 1);
    int x = v;
#pragma unroll
    for (int off = 1; off < 64; off <<= 1) {
      int t = __shfl_up(x, off);
      if (lane >= off) x += t;
    }
    if (lane == 63) wsum[wid + 1] = x;
    __syncthreads();
    if (threadIdx.x == 0) {
      wsum[0] = carry_s;
      for (int w = 1; w <= 16; ++w) wsum[w] += wsum[w - 1];
      carry_s = wsum[16];
    }
    __syncthreads();
    int excl = wsum[wid] + x - v;
    if (i < n) {
      rowptr[i] = excl;
      cursor[i] = excl;
    }
    __syncthreads();
  }
  if (threadIdx.x == 0) rowptr[n] = carry_s;
}

__global__ __launch_bounds__(256) void fill_kernel(const int* __restrict__ src,
                                                   const int* __restrict__ dst,
                                                   int* __restrict__ cursor,
                                                   int* __restrict__ esrc, int E) {
  int e = blockIdx.x * 256 + threadIdx.x;
  if (e < E) {
    int p = atomicAdd(&cursor[dst[e]], 1);
    esrc[p] = src[e];
  }
}

// wave per node: batch-load 64 neighbor indices, shfl-broadcast, 4 rows in flight
template <int D>
__global__ __launch_bounds__(256) void gather_mean_kernel(
    const float* __restrict__ in, const int* __restrict__ esrc,
    const int* __restrict__ rowptr, const float* __restrict__ inv,
    float* __restrict__ meanb, int n) {
  const int node = blockIdx.x * 4 + (threadIdx.x >> 6);
  const int lane = threadIdx.x & 63;
  if (node >= n) return;
  const int beg = rowptr[node];
  const int end = rowptr[node + 1];
  const float iv = inv[node];
  if constexpr (D == 128) {
    const float2* base = (const float2*)in;
    float a0x = 0.f, a0y = 0.f, a1x = 0.f, a1y = 0.f;
    float a2x = 0.f, a2y = 0.f, a3x = 0.f, a3y = 0.f;
    for (int b = beg; b < end; b += 64) {
      int m = end - b;
      if (m > 64) m = 64;
      int myi = (lane < m) ? esrc[b + lane] : 0;
      int s = 0;
      for (; s + 4 <= m; s += 4) {
        int i0 = __shfl(myi, s);
        int i1 = __shfl(myi, s + 1);
        int i2 = __shfl(myi, s + 2);
        int i3 = __shfl(myi, s + 3);
        float2 v0 = base[(size_t)i0 * 64 + lane];
        float2 v1 = base[(size_t)i1 * 64 + lane];
        float2 v2 = base[(size_t)i2 * 64 + lane];
        float2 v3 = base[(size_t)i3 * 64 + lane];
        a0x += v0.x; a0y += v0.y;
        a1x += v1.x; a1y += v1.y;
        a2x += v2.x; a2y += v2.y;
        a3x += v3.x; a3y += v3.y;
      }
      for (; s < m; ++s) {
        int i0 = __shfl(myi, s);
        float2 v0 = base[(size_t)i0 * 64 + lane];
        a0x += v0.x; a0y += v0.y;
      }
    }
    float2 r;
    r.x = ((a0x + a1x) + (a2x + a3x)) * iv;
    r.y = ((a0y + a1y) + (a2y + a3y)) * iv;
    ((float2*)meanb)[(size_t)node * 64 + lane] = r;
  } else {
    float a0 = 0.f, a1 = 0.f, a2 = 0.f, a3 = 0.f;
    for (int b = beg; b < end; b += 64) {
      int m = end - b;
      if (m > 64) m = 64;
      int myi = (lane < m) ? esrc[b + lane] : 0;
      int s = 0;
      for (; s + 4 <= m; s += 4) {
        int i0 = __shfl(myi, s);
        int i1 = __shfl(myi, s + 1);
        int i2 = __shfl(myi, s + 2);
        int i3 = __shfl(myi, s + 3);
        a0 += in[(size_t)i0 * 64 + lane];
        a1 += in[(size_t)i1 * 64 + lane];
        a2 += in[(size_t)i2 * 64 + lane];
        a3 += in[(size_t)i3 * 64 + lane];
      }
      for (; s < m; ++s) {
        int i0 = __shfl(myi, s);
        a0 += in[(size_t)i0 * 64 + lane];
      }
    }
    meanb[(size_t)node * 64 + lane] = ((a0 + a1) + (a2 + a3)) * iv;
  }
}

// thread per node: mean over 4-wide (padded float4) rows
__global__ __launch_bounds__(256) void gather_mean4_kernel(
    const float* __restrict__ y4, const int* __restrict__ esrc,
    const int* __restrict__ rowptr, const float* __restrict__ inv,
    float* __restrict__ mean4, int n) {
  int i = blockIdx.x * 256 + threadIdx.x;
  if (i >= n) return;
  const int beg = rowptr[i], end = rowptr[i + 1];
  const float iv = inv[i];
  float sx = 0.f, sy = 0.f, sz = 0.f;
  const float4* b = (const float4*)y4;
  for (int j = beg; j < end; ++j) {
    float4 v = b[esrc[j]];
    sx += v.x; sy += v.y; sz += v.z;
  }
  ((float4*)mean4)[i] = make_float4(sx * iv, sy * iv, sz * iv, 0.f);
}

// out[row,col] = act( (AGG ? mean@Wl^T : 0) + (ADDMEAN ? mean : 0)
//                     + in@Wr^T + (BIAS ? b : 0) )
// 128-row blocks, 256 threads: thread (tx,ty) rows ty*8..+7,
// cols {tx*4..+3} (+ {64+tx*4..+3} for DO=128).
// LDS XOR swizzle: element col of k-row kk stored at ((col>>2)^((kk>>2)&7))*4+(col&3).
template <int DI, int DO, int ACT, bool AGG, bool ADDMEAN, bool BIAS>
__global__ __launch_bounds__(256, 4) void node_kernel(
    const float* __restrict__ in, const float* __restrict__ meanb,
    const float* __restrict__ Wl, const float* __restrict__ Wr,
    const float* __restrict__ bias, float* __restrict__ out,
    float* __restrict__ out2, int n) {
  constexpr int BM = 128;
  constexpr int KC = 32;
  constexpr int TM = 8;
  constexpr int TN = DO / 16;  // 8 for DO=128, 4 for DO=64
  constexpr int NU = TN / 4;
  __shared__ __align__(16) float As[KC * BM];
  __shared__ __align__(16) float Ws[KC * DO];

  const int tx = threadIdx.x & 15;
  const int ty = threadIdx.x >> 4;
  const int row0 = blockIdx.x * BM;

  float acc[TM][TN];
#pragma unroll
  for (int r = 0; r < TM; ++r)
#pragma unroll
    for (int j = 0; j < TN; ++j) acc[r][j] = 0.f;

  const int nphase = AGG ? 2 : 1;
  for (int phase = 0; phase < nphase; ++phase) {
    const float* W = (phase == 0) ? Wr : Wl;
    const float* A = (phase == 0) ? in : meanb;
    for (int k0 = 0; k0 < DI; k0 += KC) {
      // stage A: item (r, q0): load A[row0+r][k0+4q0..+3], scatter to k-rows
      {
        int r = threadIdx.x >> 3;          // 0..31 (+32/iter)
        const int q0 = threadIdx.x & 7;    // 0..7
#pragma unroll
        for (int it = 0; it < BM / 32; ++it, r += 32) {
          int row = row0 + r;
          float4 v = make_float4(0.f, 0.f, 0.f, 0.f);
          if (row < n) v = *(const float4*)(A + (size_t)row * DI + k0 + q0 * 4);
          const int colp = (((r >> 2) ^ q0) << 2) + (r & 3);
          As[(q0 * 4 + 0) * BM + colp] = v.x;
          As[(q0 * 4 + 1) * BM + colp] = v.y;
          As[(q0 * 4 + 2) * BM + colp] = v.z;
          As[(q0 * 4 + 3) * BM + colp] = v.w;
        }
      }
      // stage W: item (c, q0): load W[c][k0+4q0..+3]
      {
        int c = threadIdx.x >> 3;
        const int q0 = threadIdx.x & 7;
#pragma unroll
        for (int it = 0; it < DO / 32; ++it, c += 32) {
          float4 v = *(const float4*)(W + (size_t)c * DI + k0 + q0 * 4);
          const int colp = (((c >> 2) ^ q0) << 2) + (c & 3);
          Ws[(q0 * 4 + 0) * DO + colp] = v.x;
          Ws[(q0 * 4 + 1) * DO + colp] = v.y;
          Ws[(q0 * 4 + 2) * DO + colp] = v.z;
          Ws[(q0 * 4 + 3) * DO + colp] = v.w;
        }
      }
      __syncthreads();
#pragma unroll
      for (int kk4 = 0; kk4 < KC / 4; ++kk4) {
        const int gg = kk4 & 7;
        const int a0off = ((2 * ty) ^ gg) << 2;
        const int a1off = ((2 * ty + 1) ^ gg) << 2;
        const int w0off = (tx ^ gg) << 2;
#pragma unroll
        for (int d = 0; d < 4; ++d) {
          const int kk = kk4 * 4 + d;
          const float* Ar = As + kk * BM;
          const float* Wr_ = Ws + kk * DO;
          const float4 a0 = *(const float4*)(Ar + a0off);
          const float4 a1 = *(const float4*)(Ar + a1off);
          const float4 w0 = *(const float4*)(Wr_ + w0off);
          float av[TM] = {a0.x, a0.y, a0.z, a0.w, a1.x, a1.y, a1.z, a1.w};
          float wv[TN];
          wv[0] = w0.x; wv[1] = w0.y; wv[2] = w0.z; wv[3] = w0.w;
          if constexpr (NU == 2) {
            const float4 w1 = *(const float4*)(Wr_ + w0off + 64);
            wv[4] = w1.x; wv[5] = w1.y; wv[6] = w1.z; wv[7] = w1.w;
          }
#pragma unroll
          for (int r = 0; r < TM; ++r)
#pragma unroll
            for (int j = 0; j < TN; ++j) acc[r][j] += av[r] * wv[j];
        }
      }
      __syncthreads();
    }
  }

  // epilogue
#pragma unroll
  for (int r = 0; r < TM; ++r) {
    int row = row0 + ty * TM + r;
    if (row >= n) continue;
#pragma unroll
    for (int u = 0; u < NU; ++u) {
      const int col = u * 64 + tx * 4;
      float v[4];
#pragma unroll
      for (int j = 0; j < 4; ++j) {
        float t = acc[r][u * 4 + j];
        if (BIAS) t += bias[col + j];
        if (ADDMEAN) t += meanb[(size_t)row * DO + col + j];
        if (ACT == ACT_TANH) t = tanhf(t);
        else if (ACT == ACT_LEAKY) t = (t > 0.f) ? t : 0.01f * t;
        v[j] = t;
      }
      float4 q = make_float4(v[0], v[1], v[2], v[3]);
      *(float4*)(out + (size_t)row * DO + col) = q;
      if (out2) *(float4*)(out2 + (size_t)row * DO + col) = q;
    }
  }
}

// y4[node] = hB[node] @ Wl^T (3 outputs, padded float4); wave per node
__global__ __launch_bounds__(256) void dec4_pre_kernel(
    const float* __restrict__ hB, const float* __restrict__ Wl,
    float* __restrict__ y4, int n) {
  const int node = blockIdx.x * 4 + (threadIdx.x >> 6);
  const int lane = threadIdx.x & 63;
  if (node >= n) return;
  float v = hB[(size_t)node * 64 + lane];
  float p0 = v * Wl[lane];
  float p1 = v * Wl[64 + lane];
  float p2 = v * Wl[128 + lane];
#pragma unroll
  for (int off = 32; off >= 1; off >>= 1) {
    p0 += __shfl_xor(p0, off);
    p1 += __shfl_xor(p1, off);
    p2 += __shfl_xor(p2, off);
  }
  if (lane == 0) ((float4*)y4)[node] = make_float4(p0, p1, p2, 0.f);
}

// out = mean4 + b + hB@Wr^T, scattered layout (z2[:,:2], z2[:,2]); wave/node
__global__ __launch_bounds__(256) void dec4_final_kernel(
    const float* __restrict__ hB, const float* __restrict__ mean4,
    const float* __restrict__ Wr, const float* __restrict__ bias,
    float* __restrict__ out, int n) {
  const int node = blockIdx.x * 4 + (threadIdx.x >> 6);
  const int lane = threadIdx.x & 63;
  if (node >= n) return;
  float v = hB[(size_t)node * 64 + lane];
  float p0 = v * Wr[lane];
  float p1 = v * Wr[64 + lane];
  float p2 = v * Wr[128 + lane];
#pragma unroll
  for (int off = 32; off >= 1; off >>= 1) {
    p0 += __shfl_xor(p0, off);
    p1 += __shfl_xor(p1, off);
    p2 += __shfl_xor(p2, off);
  }
  if (lane == 0) {
    float4 m = ((const float4*)mean4)[node];
    out[2 * (size_t)node]     = p0 + m.x + bias[0];
    out[2 * (size_t)node + 1] = p1 + m.y + bias[1];
    out[2 * (size_t)n + node] = p2 + m.z + bias[2];
  }
}

extern "C" void kernel_launch(void* const* d_in, const int* in_sizes, int n_in,
                              void* d_out, int out_size, void* d_ws, size_t ws_size,
                              hipStream_t stream) {
  const float* x = (const float*)d_in[0];
  const int* ei = (const int*)d_in[1];
  const int N = in_sizes[0] / 64;
  const int E = in_sizes[1] / 2;
  const int* src = ei;
  const int* dst = ei + E;
  const float* g1Wl = (const float*)d_in[2];
  const float* g1b  = (const float*)d_in[3];
  const float* g1Wr = (const float*)d_in[4];
  const float* g2Wl = (const float*)d_in[5];
  const float* g2b  = (const float*)d_in[6];
  const float* g2Wr = (const float*)d_in[7];
  const float* g3Wl = (const float*)d_in[8];
  const float* g3b  = (const float*)d_in[9];
  const float* g3Wr = (const float*)d_in[10];
  const float* t2W  = (const float*)d_in[11];
  const float* t2b  = (const float*)d_in[12];
  const float* d1W  = (const float*)d_in[13];
  const float* d1b  = (const float*)d_in[14];
  const float* d2Wl = (const float*)d_in[15];
  const float* d2b  = (const float*)d_in[16];
  const float* d2Wr = (const float*)d_in[17];
  const float* d3Wl = (const float*)d_in[18];
  const float* d3b  = (const float*)d_in[19];
  const float* d3Wr = (const float*)d_in[20];
  const float* d4Wl = (const float*)d_in[21];
  const float* d4b  = (const float*)d_in[22];
  const float* d4Wr = (const float*)d_in[23];

  float* ws = (float*)d_ws;
  const size_t N128 = (size_t)N * 128;
  float* hA   = ws;                        // N x 128
  float* hB   = ws + N128;                 // N x 128
  float* mean = ws + 2 * N128;             // N x 128 (also hosts y3/mean3, y4/mean4)
  int*   cnt  = (int*)(ws + 3 * N128);     // N
  float* inv  = ws + 3 * N128 + N;         // N
  int*   rowp = (int*)(ws + 3 * N128 + 2 * (size_t)N);      // N+1
  int*   curs = (int*)(ws + 3 * N128 + 3 * (size_t)N + 1);  // N
  int*   esrc = (int*)(ws + 3 * N128 + 4 * (size_t)N + 2);  // E

  float* y3    = mean;                   // N x 64
  float* mean3 = mean + (size_t)N * 64;  // N x 64
  float* y4    = mean;                   // N x 4
  float* mean4 = mean + (size_t)N * 4;   // N x 4

  float* out = (float*)d_out;
  float* mu  = out + 3 * (size_t)N;  // N x 64
  float* lv  = mu + 64 * (size_t)N;  // N x 64 (logvar == mu)

  const int NB = (N + 127) / 128;
  const int GB = (N + 3) / 4;

  // --- CSR build ---
  hipMemsetAsync(cnt, 0, (size_t)N * sizeof(int), stream);
  count_kernel<<<(E + 255) / 256, 256, 0, stream>>>(dst, cnt, E);
  scan_kernel<<<1, 1024, 0, stream>>>(cnt, rowp, curs, inv, N);
  fill_kernel<<<(E + 255) / 256, 256, 0, stream>>>(src, dst, curs, esrc, E);

  // ggn1: x(64) -> hA(128), tanh
  gather_mean_kernel<64><<<GB, 256, 0, stream>>>(x, esrc, rowp, inv, mean, N);
  node_kernel<64, 128, ACT_TANH, true, false, true><<<NB, 256, 0, stream>>>(
      x, mean, g1Wl, g1Wr, g1b, hA, nullptr, N);

  // ggn2: hA -> hB, tanh
  gather_mean_kernel<128><<<GB, 256, 0, stream>>>(hA, esrc, rowp, inv, mean, N);
  node_kernel<128, 128, ACT_TANH, true, false, true><<<NB, 256, 0, stream>>>(
      hA, mean, g2Wl, g2Wr, g2b, hB, nullptr, N);

  // ggn3: hB -> hA, tanh
  gather_mean_kernel<128><<<GB, 256, 0, stream>>>(hB, esrc, rowp, inv, mean, N);
  node_kernel<128, 128, ACT_TANH, true, false, true><<<NB, 256, 0, stream>>>(
      hB, mean, g3Wl, g3Wr, g3b, hA, nullptr, N);

  // tr2: hA(128) -> mu(64) and logvar(64)
  node_kernel<128, 64, ACT_NONE, false, false, true><<<NB, 256, 0, stream>>>(
      hA, nullptr, nullptr, t2W, t2b, mu, lv, N);

  // dec1: mu(64) -> hB(128), leaky
  node_kernel<64, 128, ACT_LEAKY, false, false, true><<<NB, 256, 0, stream>>>(
      mu, nullptr, nullptr, d1W, d1b, hB, nullptr, N);

  // dec2: hB -> hA, leaky
  gather_mean_kernel<128><<<GB, 256, 0, stream>>>(hB, esrc, rowp, inv, mean, N);
  node_kernel<128, 128, ACT_LEAKY, true, false, true><<<NB, 256, 0, stream>>>(
      hB, mean, d2Wl, d2Wr, d2b, hA, nullptr, N);

  // dec3 (linearity): y3 = hA@Wl^T; gather y3 -> mean3; hB = tanh(mean3 + hA@Wr + b)
  node_kernel<128, 64, ACT_NONE, false, false, false><<<NB, 256, 0, stream>>>(
      hA, nullptr, nullptr, d3Wl, nullptr, y3, nullptr, N);
  gather_mean_kernel<64><<<GB, 256, 0, stream>>>(y3, esrc, rowp, inv, mean3, N);
  node_kernel<128, 64, ACT_TANH, false, true, true><<<NB, 256, 0, stream>>>(
      hA, mean3, nullptr, d3Wr, d3b, hB, nullptr, N);

  // dec4 (linearity): y4 = hB@Wl^T (3-pad-4); gather4; out = mean4 + b + hB@Wr
  dec4_pre_kernel<<<GB, 256, 0, stream>>>(hB, d4Wl, y4, N);
  gather_mean4_kernel<<<(N + 255) / 256, 256, 0, stream>>>(y4, esrc, rowp, inv, mean4, N);
  dec4_final_kernel<<<GB, 256, 0, stream>>>(hB, mean4, d4Wr, d4b, out, N);
}

// Round 5
// 1511.948 us; speedup vs baseline: 9.5402x; 1.0526x over previous
//
#include <hip/hip_runtime.h>
#include <cmath>

// ---------------------------------------------------------------------------
// GCN_Message: graph VAE forward. Round 5:
//   - node_kernel: __launch_bounds__(256,2) — R4's (256,4) capped VGPRs at 64
//     and spilled the 8x8 accumulator to scratch (WRITE_SIZE 231 MB vs 51 MB
//     output). Cap 256 -> ~130-160 VGPR, no spill, ~3 blocks/CU (VGPR-bound,
//     LDS is only 32 KB now).
//   - XOR-swizzled LDS (0 bank conflicts, verified R4)
//   - gather v2: batch-load 64 neighbor indices, shfl broadcast, 4 rows in
//     flight per wave
//   - linearity of mean for dec3/dec4 (gather in output space)
// ---------------------------------------------------------------------------

constexpr int ACT_NONE = 0, ACT_TANH = 1, ACT_LEAKY = 2;

__global__ __launch_bounds__(256) void count_kernel(const int* __restrict__ dst,
                                                    int* __restrict__ cnt, int E) {
  int e = blockIdx.x * 256 + threadIdx.x;
  if (e < E) atomicAdd(&cnt[dst[e]], 1);
}

// single-workgroup exclusive scan over cnt -> rowptr, cursor; also inv = 1/max(cnt,1)
__global__ __launch_bounds__(1024) void scan_kernel(const int* __restrict__ cnt,
                                                    int* __restrict__ rowptr,
                                                    int* __restrict__ cursor,
                                                    float* __restrict__ inv, int n) {
  __shared__ int wsum[17];
  __shared__ int carry_s;
  const int lane = threadIdx.x & 63;
  const int wid = threadIdx.x >> 6;
  if (threadIdx.x == 0) carry_s = 0;
  __syncthreads();
  for (int base = 0; base < n; base += 1024) {
    int i = base + threadIdx.x;
    int v = (i < n) ? cnt[i] : 0;
    if (i < n) inv[i] = 1.0f / (float)(v > 1 ? v : 1);
    int x = v;
#pragma unroll
    for (int off = 1; off < 64; off <<= 1) {
      int t = __shfl_up(x, off);
      if (lane >= off) x += t;
    }
    if (lane == 63) wsum[wid + 1] = x;
    __syncthreads();
    if (threadIdx.x == 0) {
      wsum[0] = carry_s;
      for (int w = 1; w <= 16; ++w) wsum[w] += wsum[w - 1];
      carry_s = wsum[16];
    }
    __syncthreads();
    int excl = wsum[wid] + x - v;
    if (i < n) {
      rowptr[i] = excl;
      cursor[i] = excl;
    }
    __syncthreads();
  }
  if (threadIdx.x == 0) rowptr[n] = carry_s;
}

__global__ __launch_bounds__(256) void fill_kernel(const int* __restrict__ src,
                                                   const int* __restrict__ dst,
                                                   int* __restrict__ cursor,
                                                   int* __restrict__ esrc, int E) {
  int e = blockIdx.x * 256 + threadIdx.x;
  if (e < E) {
    int p = atomicAdd(&cursor[dst[e]], 1);
    esrc[p] = src[e];
  }
}

// wave per node: batch-load 64 neighbor indices, shfl-broadcast, 4 rows in flight
template <int D>
__global__ __launch_bounds__(256) void gather_mean_kernel(
    const float* __restrict__ in, const int* __restrict__ esrc,
    const int* __restrict__ rowptr, const float* __restrict__ inv,
    float* __restrict__ meanb, int n) {
  const int node = blockIdx.x * 4 + (threadIdx.x >> 6);
  const int lane = threadIdx.x & 63;
  if (node >= n) return;
  const int beg = rowptr[node];
  const int end = rowptr[node + 1];
  const float iv = inv[node];
  if constexpr (D == 128) {
    const float2* base = (const float2*)in;
    float a0x = 0.f, a0y = 0.f, a1x = 0.f, a1y = 0.f;
    float a2x = 0.f, a2y = 0.f, a3x = 0.f, a3y = 0.f;
    for (int b = beg; b < end; b += 64) {
      int m = end - b;
      if (m > 64) m = 64;
      int myi = (lane < m) ? esrc[b + lane] : 0;
      int s = 0;
      for (; s + 4 <= m; s += 4) {
        int i0 = __shfl(myi, s);
        int i1 = __shfl(myi, s + 1);
        int i2 = __shfl(myi, s + 2);
        int i3 = __shfl(myi, s + 3);
        float2 v0 = base[(size_t)i0 * 64 + lane];
        float2 v1 = base[(size_t)i1 * 64 + lane];
        float2 v2 = base[(size_t)i2 * 64 + lane];
        float2 v3 = base[(size_t)i3 * 64 + lane];
        a0x += v0.x; a0y += v0.y;
        a1x += v1.x; a1y += v1.y;
        a2x += v2.x; a2y += v2.y;
        a3x += v3.x; a3y += v3.y;
      }
      for (; s < m; ++s) {
        int i0 = __shfl(myi, s);
        float2 v0 = base[(size_t)i0 * 64 + lane];
        a0x += v0.x; a0y += v0.y;
      }
    }
    float2 r;
    r.x = ((a0x + a1x) + (a2x + a3x)) * iv;
    r.y = ((a0y + a1y) + (a2y + a3y)) * iv;
    ((float2*)meanb)[(size_t)node * 64 + lane] = r;
  } else {
    float a0 = 0.f, a1 = 0.f, a2 = 0.f, a3 = 0.f;
    for (int b = beg; b < end; b += 64) {
      int m = end - b;
      if (m > 64) m = 64;
      int myi = (lane < m) ? esrc[b + lane] : 0;
      int s = 0;
      for (; s + 4 <= m; s += 4) {
        int i0 = __shfl(myi, s);
        int i1 = __shfl(myi, s + 1);
        int i2 = __shfl(myi, s + 2);
        int i3 = __shfl(myi, s + 3);
        a0 += in[(size_t)i0 * 64 + lane];
        a1 += in[(size_t)i1 * 64 + lane];
        a2 += in[(size_t)i2 * 64 + lane];
        a3 += in[(size_t)i3 * 64 + lane];
      }
      for (; s < m; ++s) {
        int i0 = __shfl(myi, s);
        a0 += in[(size_t)i0 * 64 + lane];
      }
    }
    meanb[(size_t)node * 64 + lane] = ((a0 + a1) + (a2 + a3)) * iv;
  }
}

// thread per node: mean over 4-wide (padded float4) rows
__global__ __launch_bounds__(256) void gather_mean4_kernel(
    const float* __restrict__ y4, const int* __restrict__ esrc,
    const int* __restrict__ rowptr, const float* __restrict__ inv,
    float* __restrict__ mean4, int n) {
  int i = blockIdx.x * 256 + threadIdx.x;
  if (i >= n) return;
  const int beg = rowptr[i], end = rowptr[i + 1];
  const float iv = inv[i];
  float sx = 0.f, sy = 0.f, sz = 0.f;
  const float4* b = (const float4*)y4;
  for (int j = beg; j < end; ++j) {
    float4 v = b[esrc[j]];
    sx += v.x; sy += v.y; sz += v.z;
  }
  ((float4*)mean4)[i] = make_float4(sx * iv, sy * iv, sz * iv, 0.f);
}

// out[row,col] = act( (AGG ? mean@Wl^T : 0) + (ADDMEAN ? mean : 0)
//                     + in@Wr^T + (BIAS ? b : 0) )
// 128-row blocks, 256 threads: thread (tx,ty) rows ty*8..+7,
// cols {tx*4..+3} (+ {64+tx*4..+3} for DO=128).
// LDS XOR swizzle: element col of k-row kk stored at ((col>>2)^((kk>>2)&7))*4+(col&3).
template <int DI, int DO, int ACT, bool AGG, bool ADDMEAN, bool BIAS>
__global__ __launch_bounds__(256, 2) void node_kernel(
    const float* __restrict__ in, const float* __restrict__ meanb,
    const float* __restrict__ Wl, const float* __restrict__ Wr,
    const float* __restrict__ bias, float* __restrict__ out,
    float* __restrict__ out2, int n) {
  constexpr int BM = 128;
  constexpr int KC = 32;
  constexpr int TM = 8;
  constexpr int TN = DO / 16;  // 8 for DO=128, 4 for DO=64
  constexpr int NU = TN / 4;
  __shared__ __align__(16) float As[KC * BM];
  __shared__ __align__(16) float Ws[KC * DO];

  const int tx = threadIdx.x & 15;
  const int ty = threadIdx.x >> 4;
  const int row0 = blockIdx.x * BM;

  float acc[TM][TN];
#pragma unroll
  for (int r = 0; r < TM; ++r)
#pragma unroll
    for (int j = 0; j < TN; ++j) acc[r][j] = 0.f;

  const int nphase = AGG ? 2 : 1;
  for (int phase = 0; phase < nphase; ++phase) {
    const float* W = (phase == 0) ? Wr : Wl;
    const float* A = (phase == 0) ? in : meanb;
    for (int k0 = 0; k0 < DI; k0 += KC) {
      // stage A: item (r, q0): load A[row0+r][k0+4q0..+3], scatter to k-rows
      {
        int r = threadIdx.x >> 3;          // 0..31 (+32/iter)
        const int q0 = threadIdx.x & 7;    // 0..7
#pragma unroll
        for (int it = 0; it < BM / 32; ++it, r += 32) {
          int row = row0 + r;
          float4 v = make_float4(0.f, 0.f, 0.f, 0.f);
          if (row < n) v = *(const float4*)(A + (size_t)row * DI + k0 + q0 * 4);
          const int colp = (((r >> 2) ^ q0) << 2) + (r & 3);
          As[(q0 * 4 + 0) * BM + colp] = v.x;
          As[(q0 * 4 + 1) * BM + colp] = v.y;
          As[(q0 * 4 + 2) * BM + colp] = v.z;
          As[(q0 * 4 + 3) * BM + colp] = v.w;
        }
      }
      // stage W: item (c, q0): load W[c][k0+4q0..+3]
      {
        int c = threadIdx.x >> 3;
        const int q0 = threadIdx.x & 7;
#pragma unroll
        for (int it = 0; it < DO / 32; ++it, c += 32) {
          float4 v = *(const float4*)(W + (size_t)c * DI + k0 + q0 * 4);
          const int colp = (((c >> 2) ^ q0) << 2) + (c & 3);
          Ws[(q0 * 4 + 0) * DO + colp] = v.x;
          Ws[(q0 * 4 + 1) * DO + colp] = v.y;
          Ws[(q0 * 4 + 2) * DO + colp] = v.z;
          Ws[(q0 * 4 + 3) * DO + colp] = v.w;
        }
      }
      __syncthreads();
#pragma unroll
      for (int kk4 = 0; kk4 < KC / 4; ++kk4) {
        const int gg = kk4 & 7;
        const int a0off = ((2 * ty) ^ gg) << 2;
        const int a1off = ((2 * ty + 1) ^ gg) << 2;
        const int w0off = (tx ^ gg) << 2;
#pragma unroll
        for (int d = 0; d < 4; ++d) {
          const int kk = kk4 * 4 + d;
          const float* Ar = As + kk * BM;
          const float* Wr_ = Ws + kk * DO;
          const float4 a0 = *(const float4*)(Ar + a0off);
          const float4 a1 = *(const float4*)(Ar + a1off);
          const float4 w0 = *(const float4*)(Wr_ + w0off);
          float av[TM] = {a0.x, a0.y, a0.z, a0.w, a1.x, a1.y, a1.z, a1.w};
          float wv[TN];
          wv[0] = w0.x; wv[1] = w0.y; wv[2] = w0.z; wv[3] = w0.w;
          if constexpr (NU == 2) {
            const float4 w1 = *(const float4*)(Wr_ + w0off + 64);
            wv[4] = w1.x; wv[5] = w1.y; wv[6] = w1.z; wv[7] = w1.w;
          }
#pragma unroll
          for (int r = 0; r < TM; ++r)
#pragma unroll
            for (int j = 0; j < TN; ++j) acc[r][j] += av[r] * wv[j];
        }
      }
      __syncthreads();
    }
  }

  // epilogue
#pragma unroll
  for (int r = 0; r < TM; ++r) {
    int row = row0 + ty * TM + r;
    if (row >= n) continue;
#pragma unroll
    for (int u = 0; u < NU; ++u) {
      const int col = u * 64 + tx * 4;
      float v[4];
#pragma unroll
      for (int j = 0; j < 4; ++j) {
        float t = acc[r][u * 4 + j];
        if (BIAS) t += bias[col + j];
        if (ADDMEAN) t += meanb[(size_t)row * DO + col + j];
        if (ACT == ACT_TANH) t = tanhf(t);
        else if (ACT == ACT_LEAKY) t = (t > 0.f) ? t : 0.01f * t;
        v[j] = t;
      }
      float4 q = make_float4(v[0], v[1], v[2], v[3]);
      *(float4*)(out + (size_t)row * DO + col) = q;
      if (out2) *(float4*)(out2 + (size_t)row * DO + col) = q;
    }
  }
}

// y4[node] = hB[node] @ Wl^T (3 outputs, padded float4); wave per node
__global__ __launch_bounds__(256) void dec4_pre_kernel(
    const float* __restrict__ hB, const float* __restrict__ Wl,
    float* __restrict__ y4, int n) {
  const int node = blockIdx.x * 4 + (threadIdx.x >> 6);
  const int lane = threadIdx.x & 63;
  if (node >= n) return;
  float v = hB[(size_t)node * 64 + lane];
  float p0 = v * Wl[lane];
  float p1 = v * Wl[64 + lane];
  float p2 = v * Wl[128 + lane];
#pragma unroll
  for (int off = 32; off >= 1; off >>= 1) {
    p0 += __shfl_xor(p0, off);
    p1 += __shfl_xor(p1, off);
    p2 += __shfl_xor(p2, off);
  }
  if (lane == 0) ((float4*)y4)[node] = make_float4(p0, p1, p2, 0.f);
}

// out = mean4 + b + hB@Wr^T, scattered layout (z2[:,:2], z2[:,2]); wave/node
__global__ __launch_bounds__(256) void dec4_final_kernel(
    const float* __restrict__ hB, const float* __restrict__ mean4,
    const float* __restrict__ Wr, const float* __restrict__ bias,
    float* __restrict__ out, int n) {
  const int node = blockIdx.x * 4 + (threadIdx.x >> 6);
  const int lane = threadIdx.x & 63;
  if (node >= n) return;
  float v = hB[(size_t)node * 64 + lane];
  float p0 = v * Wr[lane];
  float p1 = v * Wr[64 + lane];
  float p2 = v * Wr[128 + lane];
#pragma unroll
  for (int off = 32; off >= 1; off >>= 1) {
    p0 += __shfl_xor(p0, off);
    p1 += __shfl_xor(p1, off);
    p2 += __shfl_xor(p2, off);
  }
  if (lane == 0) {
    float4 m = ((const float4*)mean4)[node];
    out[2 * (size_t)node]     = p0 + m.x + bias[0];
    out[2 * (size_t)node + 1] = p1 + m.y + bias[1];
    out[2 * (size_t)n + node] = p2 + m.z + bias[2];
  }
}

extern "C" void kernel_launch(void* const* d_in, const int* in_sizes, int n_in,
                              void* d_out, int out_size, void* d_ws, size_t ws_size,
                              hipStream_t stream) {
  const float* x = (const float*)d_in[0];
  const int* ei = (const int*)d_in[1];
  const int N = in_sizes[0] / 64;
  const int E = in_sizes[1] / 2;
  const int* src = ei;
  const int* dst = ei + E;
  const float* g1Wl = (const float*)d_in[2];
  const float* g1b  = (const float*)d_in[3];
  const float* g1Wr = (const float*)d_in[4];
  const float* g2Wl = (const float*)d_in[5];
  const float* g2b  = (const float*)d_in[6];
  const float* g2Wr = (const float*)d_in[7];
  const float* g3Wl = (const float*)d_in[8];
  const float* g3b  = (const float*)d_in[9];
  const float* g3Wr = (const float*)d_in[10];
  const float* t2W  = (const float*)d_in[11];
  const float* t2b  = (const float*)d_in[12];
  const float* d1W  = (const float*)d_in[13];
  const float* d1b  = (const float*)d_in[14];
  const float* d2Wl = (const float*)d_in[15];
  const float* d2b  = (const float*)d_in[16];
  const float* d2Wr = (const float*)d_in[17];
  const float* d3Wl = (const float*)d_in[18];
  const float* d3b  = (const float*)d_in[19];
  const float* d3Wr = (const float*)d_in[20];
  const float* d4Wl = (const float*)d_in[21];
  const float* d4b  = (const float*)d_in[22];
  const float* d4Wr = (const float*)d_in[23];

  float* ws = (float*)d_ws;
  const size_t N128 = (size_t)N * 128;
  float* hA   = ws;                        // N x 128
  float* hB   = ws + N128;                 // N x 128
  float* mean = ws + 2 * N128;             // N x 128 (also hosts y3/mean3, y4/mean4)
  int*   cnt  = (int*)(ws + 3 * N128);     // N
  float* inv  = ws + 3 * N128 + N;         // N
  int*   rowp = (int*)(ws + 3 * N128 + 2 * (size_t)N);      // N+1
  int*   curs = (int*)(ws + 3 * N128 + 3 * (size_t)N + 1);  // N
  int*   esrc = (int*)(ws + 3 * N128 + 4 * (size_t)N + 2);  // E

  float* y3    = mean;                   // N x 64
  float* mean3 = mean + (size_t)N * 64;  // N x 64
  float* y4    = mean;                   // N x 4
  float* mean4 = mean + (size_t)N * 4;   // N x 4

  float* out = (float*)d_out;
  float* mu  = out + 3 * (size_t)N;  // N x 64
  float* lv  = mu + 64 * (size_t)N;  // N x 64 (logvar == mu)

  const int NB = (N + 127) / 128;
  const int GB = (N + 3) / 4;

  // --- CSR build ---
  hipMemsetAsync(cnt, 0, (size_t)N * sizeof(int), stream);
  count_kernel<<<(E + 255) / 256, 256, 0, stream>>>(dst, cnt, E);
  scan_kernel<<<1, 1024, 0, stream>>>(cnt, rowp, curs, inv, N);
  fill_kernel<<<(E + 255) / 256, 256, 0, stream>>>(src, dst, curs, esrc, E);

  // ggn1: x(64) -> hA(128), tanh
  gather_mean_kernel<64><<<GB, 256, 0, stream>>>(x, esrc, rowp, inv, mean, N);
  node_kernel<64, 128, ACT_TANH, true, false, true><<<NB, 256, 0, stream>>>(
      x, mean, g1Wl, g1Wr, g1b, hA, nullptr, N);

  // ggn2: hA -> hB, tanh
  gather_mean_kernel<128><<<GB, 256, 0, stream>>>(hA, esrc, rowp, inv, mean, N);
  node_kernel<128, 128, ACT_TANH, true, false, true><<<NB, 256, 0, stream>>>(
      hA, mean, g2Wl, g2Wr, g2b, hB, nullptr, N);

  // ggn3: hB -> hA, tanh
  gather_mean_kernel<128><<<GB, 256, 0, stream>>>(hB, esrc, rowp, inv, mean, N);
  node_kernel<128, 128, ACT_TANH, true, false, true><<<NB, 256, 0, stream>>>(
      hB, mean, g3Wl, g3Wr, g3b, hA, nullptr, N);

  // tr2: hA(128) -> mu(64) and logvar(64)
  node_kernel<128, 64, ACT_NONE, false, false, true><<<NB, 256, 0, stream>>>(
      hA, nullptr, nullptr, t2W, t2b, mu, lv, N);

  // dec1: mu(64) -> hB(128), leaky
  node_kernel<64, 128, ACT_LEAKY, false, false, true><<<NB, 256, 0, stream>>>(
      mu, nullptr, nullptr, d1W, d1b, hB, nullptr, N);

  // dec2: hB -> hA, leaky
  gather_mean_kernel<128><<<GB, 256, 0, stream>>>(hB, esrc, rowp, inv, mean, N);
  node_kernel<128, 128, ACT_LEAKY, true, false, true><<<NB, 256, 0, stream>>>(
      hB, mean, d2Wl, d2Wr, d2b, hA, nullptr, N);

  // dec3 (linearity): y3 = hA@Wl^T; gather y3 -> mean3; hB = tanh(mean3 + hA@Wr + b)
  node_kernel<128, 64, ACT_NONE, false, false, false><<<NB, 256, 0, stream>>>(
      hA, nullptr, nullptr, d3Wl, nullptr, y3, nullptr, N);
  gather_mean_kernel<64><<<GB, 256, 0, stream>>>(y3, esrc, rowp, inv, mean3, N);
  node_kernel<128, 64, ACT_TANH, false, true, true><<<NB, 256, 0, stream>>>(
      hA, mean3, nullptr, d3Wr, d3b, hB, nullptr, N);

  // dec4 (linearity): y4 = hB@Wl^T (3-pad-4); gather4; out = mean4 + b + hB@Wr
  dec4_pre_kernel<<<GB, 256, 0, stream>>>(hB, d4Wl, y4, N);
  gather_mean4_kernel<<<(N + 255) / 256, 256, 0, stream>>>(y4, esrc, rowp, inv, mean4, N);
  dec4_final_kernel<<<GB, 256, 0, stream>>>(hB, mean4, d4Wr, d4b, out, N);
}

// Round 6
// 1229.409 us; speedup vs baseline: 11.7327x; 1.2298x over previous
//
#include <hip/hip_runtime.h>
#include <cmath>

// ---------------------------------------------------------------------------
// GCN_Message: graph VAE forward. Round 6:
//   - node GEMMs -> MFMA (16x16x32 bf16) with 3-term split-bf16 emulation:
//     a = a_hi + a_lo (bf16); D += Ah*Bh + Al*Bh + Ah*Bl  (error ~2^-16, keeps
//     fp32-grade numerics; ~5x fp32 vector peak).
//     Layouts (m89/m91/m120-verified): A-frag A[m=lane&15][k=(lane>>4)*8+j],
//     B-frag W[n=lane&15][k=...] (W is B^T, k-contiguous), C/D col=lane&15,
//     row=(lane>>4)*4+reg. LDS bf16 planes, k-stride 40 (conflict-free).
//   - CSR gather v2 (shfl-broadcast), linearity-of-mean for dec3/dec4: as R5.
// ---------------------------------------------------------------------------

constexpr int ACT_NONE = 0, ACT_TANH = 1, ACT_LEAKY = 2;

typedef __attribute__((ext_vector_type(8))) __bf16 bf16x8;
typedef __attribute__((ext_vector_type(4))) float f32x4;

__global__ __launch_bounds__(256) void count_kernel(const int* __restrict__ dst,
                                                    int* __restrict__ cnt, int E) {
  int e = blockIdx.x * 256 + threadIdx.x;
  if (e < E) atomicAdd(&cnt[dst[e]], 1);
}

// single-workgroup exclusive scan over cnt -> rowptr, cursor; also inv = 1/max(cnt,1)
__global__ __launch_bounds__(1024) void scan_kernel(const int* __restrict__ cnt,
                                                    int* __restrict__ rowptr,
                                                    int* __restrict__ cursor,
                                                    float* __restrict__ inv, int n) {
  __shared__ int wsum[17];
  __shared__ int carry_s;
  const int lane = threadIdx.x & 63;
  const int wid = threadIdx.x >> 6;
  if (threadIdx.x == 0) carry_s = 0;
  __syncthreads();
  for (int base = 0; base < n; base += 1024) {
    int i = base + threadIdx.x;
    int v = (i < n) ? cnt[i] : 0;
    if (i < n) inv[i] = 1.0f / (float)(v > 1 ? v : 1);
    int x = v;
#pragma unroll
    for (int off = 1; off < 64; off <<= 1) {
      int t = __shfl_up(x, off);
      if (lane >= off) x += t;
    }
    if (lane == 63) wsum[wid + 1] = x;
    __syncthreads();
    if (threadIdx.x == 0) {
      wsum[0] = carry_s;
      for (int w = 1; w <= 16; ++w) wsum[w] += wsum[w - 1];
      carry_s = wsum[16];
    }
    __syncthreads();
    int excl = wsum[wid] + x - v;
    if (i < n) {
      rowptr[i] = excl;
      cursor[i] = excl;
    }
    __syncthreads();
  }
  if (threadIdx.x == 0) rowptr[n] = carry_s;
}

__global__ __launch_bounds__(256) void fill_kernel(const int* __restrict__ src,
                                                   const int* __restrict__ dst,
                                                   int* __restrict__ cursor,
                                                   int* __restrict__ esrc, int E) {
  int e = blockIdx.x * 256 + threadIdx.x;
  if (e < E) {
    int p = atomicAdd(&cursor[dst[e]], 1);
    esrc[p] = src[e];
  }
}

// wave per node: batch-load 64 neighbor indices, shfl-broadcast, 4 rows in flight
template <int D>
__global__ __launch_bounds__(256) void gather_mean_kernel(
    const float* __restrict__ in, const int* __restrict__ esrc,
    const int* __restrict__ rowptr, const float* __restrict__ inv,
    float* __restrict__ meanb, int n) {
  const int node = blockIdx.x * 4 + (threadIdx.x >> 6);
  const int lane = threadIdx.x & 63;
  if (node >= n) return;
  const int beg = rowptr[node];
  const int end = rowptr[node + 1];
  const float iv = inv[node];
  if constexpr (D == 128) {
    const float2* base = (const float2*)in;
    float a0x = 0.f, a0y = 0.f, a1x = 0.f, a1y = 0.f;
    float a2x = 0.f, a2y = 0.f, a3x = 0.f, a3y = 0.f;
    for (int b = beg; b < end; b += 64) {
      int m = end - b;
      if (m > 64) m = 64;
      int myi = (lane < m) ? esrc[b + lane] : 0;
      int s = 0;
      for (; s + 4 <= m; s += 4) {
        int i0 = __shfl(myi, s);
        int i1 = __shfl(myi, s + 1);
        int i2 = __shfl(myi, s + 2);
        int i3 = __shfl(myi, s + 3);
        float2 v0 = base[(size_t)i0 * 64 + lane];
        float2 v1 = base[(size_t)i1 * 64 + lane];
        float2 v2 = base[(size_t)i2 * 64 + lane];
        float2 v3 = base[(size_t)i3 * 64 + lane];
        a0x += v0.x; a0y += v0.y;
        a1x += v1.x; a1y += v1.y;
        a2x += v2.x; a2y += v2.y;
        a3x += v3.x; a3y += v3.y;
      }
      for (; s < m; ++s) {
        int i0 = __shfl(myi, s);
        float2 v0 = base[(size_t)i0 * 64 + lane];
        a0x += v0.x; a0y += v0.y;
      }
    }
    float2 r;
    r.x = ((a0x + a1x) + (a2x + a3x)) * iv;
    r.y = ((a0y + a1y) + (a2y + a3y)) * iv;
    ((float2*)meanb)[(size_t)node * 64 + lane] = r;
  } else {
    float a0 = 0.f, a1 = 0.f, a2 = 0.f, a3 = 0.f;
    for (int b = beg; b < end; b += 64) {
      int m = end - b;
      if (m > 64) m = 64;
      int myi = (lane < m) ? esrc[b + lane] : 0;
      int s = 0;
      for (; s + 4 <= m; s += 4) {
        int i0 = __shfl(myi, s);
        int i1 = __shfl(myi, s + 1);
        int i2 = __shfl(myi, s + 2);
        int i3 = __shfl(myi, s + 3);
        a0 += in[(size_t)i0 * 64 + lane];
        a1 += in[(size_t)i1 * 64 + lane];
        a2 += in[(size_t)i2 * 64 + lane];
        a3 += in[(size_t)i3 * 64 + lane];
      }
      for (; s < m; ++s) {
        int i0 = __shfl(myi, s);
        a0 += in[(size_t)i0 * 64 + lane];
      }
    }
    meanb[(size_t)node * 64 + lane] = ((a0 + a1) + (a2 + a3)) * iv;
  }
}

// thread per node: mean over 4-wide (padded float4) rows
__global__ __launch_bounds__(256) void gather_mean4_kernel(
    const float* __restrict__ y4, const int* __restrict__ esrc,
    const int* __restrict__ rowptr, const float* __restrict__ inv,
    float* __restrict__ mean4, int n) {
  int i = blockIdx.x * 256 + threadIdx.x;
  if (i >= n) return;
  const int beg = rowptr[i], end = rowptr[i + 1];
  const float iv = inv[i];
  float sx = 0.f, sy = 0.f, sz = 0.f;
  const float4* b = (const float4*)y4;
  for (int j = beg; j < end; ++j) {
    float4 v = b[esrc[j]];
    sx += v.x; sy += v.y; sz += v.z;
  }
  ((float4*)mean4)[i] = make_float4(sx * iv, sy * iv, sz * iv, 0.f);
}

__device__ __forceinline__ void split_bf16(float x, __bf16& h, __bf16& l) {
  h = (__bf16)x;
  l = (__bf16)(x - (float)h);
}

// out[row,col] = act( (AGG ? mean@Wl^T : 0) + (ADDMEAN ? mean : 0)
//                     + in@Wr^T + (BIAS ? b : 0) )
// 128-row block, 4 waves; wave wv covers rows wv*32..+31 (2 MFMA row-tiles),
// all DO cols (CT=DO/16 col-tiles). 3x split-bf16 MFMA per tile per k-chunk.
template <int DI, int DO, int ACT, bool AGG, bool ADDMEAN, bool BIAS>
__global__ __launch_bounds__(256) void node_mfma_kernel(
    const float* __restrict__ in, const float* __restrict__ meanb,
    const float* __restrict__ Wl, const float* __restrict__ Wr,
    const float* __restrict__ bias, float* __restrict__ out,
    float* __restrict__ out2, int n) {
  constexpr int BM = 128;
  constexpr int KC = 32;
  constexpr int KS = 40;       // padded k-stride in bf16 elems: (20m)%32 spread
  constexpr int CT = DO / 16;  // col tiles per wave (8 or 4)
  __shared__ __align__(16) __bf16 As_hi[BM * KS];
  __shared__ __align__(16) __bf16 As_lo[BM * KS];
  __shared__ __align__(16) __bf16 Ws_hi[DO * KS];
  __shared__ __align__(16) __bf16 Ws_lo[DO * KS];

  const int wv = threadIdx.x >> 6;
  const int lane = threadIdx.x & 63;
  const int lm = lane & 15;
  const int lq = lane >> 4;
  const int row0 = blockIdx.x * BM;

  f32x4 acc[2][CT];
#pragma unroll
  for (int rt = 0; rt < 2; ++rt)
#pragma unroll
    for (int ct = 0; ct < CT; ++ct) acc[rt][ct] = (f32x4){0.f, 0.f, 0.f, 0.f};

  const int nphase = AGG ? 2 : 1;
  for (int phase = 0; phase < nphase; ++phase) {
    const float* W = (phase == 0) ? Wr : Wl;
    const float* Amat = (phase == 0) ? in : meanb;
    for (int k0 = 0; k0 < DI; k0 += KC) {
      // ---- stage A chunk (BM x KC fp32 -> hi/lo bf16 planes) ----
      {
        const int r = threadIdx.x >> 1;
        const int kb = (threadIdx.x & 1) * 16;
        const int row = row0 + r;
        float v[16];
        if (row < n) {
          const float4* p = (const float4*)(Amat + (size_t)row * DI + k0 + kb);
#pragma unroll
          for (int i = 0; i < 4; ++i) {
            float4 t = p[i];
            v[4 * i + 0] = t.x; v[4 * i + 1] = t.y;
            v[4 * i + 2] = t.z; v[4 * i + 3] = t.w;
          }
        } else {
#pragma unroll
          for (int i = 0; i < 16; ++i) v[i] = 0.f;
        }
        bf16x8 hi[2], lo[2];
#pragma unroll
        for (int g = 0; g < 2; ++g)
#pragma unroll
          for (int i = 0; i < 8; ++i) {
            __bf16 h, l;
            split_bf16(v[g * 8 + i], h, l);
            hi[g][i] = h; lo[g][i] = l;
          }
        *(bf16x8*)(&As_hi[r * KS + kb]) = hi[0];
        *(bf16x8*)(&As_hi[r * KS + kb + 8]) = hi[1];
        *(bf16x8*)(&As_lo[r * KS + kb]) = lo[0];
        *(bf16x8*)(&As_lo[r * KS + kb + 8]) = lo[1];
      }
      // ---- stage W chunk (DO x KC) ----
      if constexpr (DO == 128) {
        const int c = threadIdx.x >> 1;
        const int kb = (threadIdx.x & 1) * 16;
        const float4* p = (const float4*)(W + (size_t)c * DI + k0 + kb);
        float v[16];
#pragma unroll
        for (int i = 0; i < 4; ++i) {
          float4 t = p[i];
          v[4 * i + 0] = t.x; v[4 * i + 1] = t.y;
          v[4 * i + 2] = t.z; v[4 * i + 3] = t.w;
        }
        bf16x8 hi[2], lo[2];
#pragma unroll
        for (int g = 0; g < 2; ++g)
#pragma unroll
          for (int i = 0; i < 8; ++i) {
            __bf16 h, l;
            split_bf16(v[g * 8 + i], h, l);
            hi[g][i] = h; lo[g][i] = l;
          }
        *(bf16x8*)(&Ws_hi[c * KS + kb]) = hi[0];
        *(bf16x8*)(&Ws_hi[c * KS + kb + 8]) = hi[1];
        *(bf16x8*)(&Ws_lo[c * KS + kb]) = lo[0];
        *(bf16x8*)(&Ws_lo[c * KS + kb + 8]) = lo[1];
      } else {
        const int c = threadIdx.x >> 2;
        const int kb = (threadIdx.x & 3) * 8;
        const float4* p = (const float4*)(W + (size_t)c * DI + k0 + kb);
        float v[8];
#pragma unroll
        for (int i = 0; i < 2; ++i) {
          float4 t = p[i];
          v[4 * i + 0] = t.x; v[4 * i + 1] = t.y;
          v[4 * i + 2] = t.z; v[4 * i + 3] = t.w;
        }
        bf16x8 hi, lo;
#pragma unroll
        for (int i = 0; i < 8; ++i) {
          __bf16 h, l;
          split_bf16(v[i], h, l);
          hi[i] = h; lo[i] = l;
        }
        *(bf16x8*)(&Ws_hi[c * KS + kb]) = hi;
        *(bf16x8*)(&Ws_lo[c * KS + kb]) = lo;
      }
      __syncthreads();
      // ---- MFMA: 3-term split-bf16 ----
      const int kb = lq * 8;
      bf16x8 ah[2], al[2];
#pragma unroll
      for (int rt = 0; rt < 2; ++rt) {
        const int r = wv * 32 + rt * 16 + lm;
        ah[rt] = *(const bf16x8*)(&As_hi[r * KS + kb]);
        al[rt] = *(const bf16x8*)(&As_lo[r * KS + kb]);
      }
#pragma unroll
      for (int ct = 0; ct < CT; ++ct) {
        const int c = ct * 16 + lm;
        bf16x8 bh = *(const bf16x8*)(&Ws_hi[c * KS + kb]);
        bf16x8 bl = *(const bf16x8*)(&Ws_lo[c * KS + kb]);
#pragma unroll
        for (int rt = 0; rt < 2; ++rt) {
          acc[rt][ct] = __builtin_amdgcn_mfma_f32_16x16x32_bf16(ah[rt], bh, acc[rt][ct], 0, 0, 0);
          acc[rt][ct] = __builtin_amdgcn_mfma_f32_16x16x32_bf16(al[rt], bh, acc[rt][ct], 0, 0, 0);
          acc[rt][ct] = __builtin_amdgcn_mfma_f32_16x16x32_bf16(ah[rt], bl, acc[rt][ct], 0, 0, 0);
        }
      }
      __syncthreads();
    }
  }

  // ---- epilogue: C/D layout col=lane&15, row=lq*4+reg ----
#pragma unroll
  for (int rt = 0; rt < 2; ++rt)
#pragma unroll
    for (int ct = 0; ct < CT; ++ct) {
      const int col = ct * 16 + lm;
      const float bval = BIAS ? bias[col] : 0.f;
      f32x4 a = acc[rt][ct];
#pragma unroll
      for (int r = 0; r < 4; ++r) {
        const int row = row0 + wv * 32 + rt * 16 + lq * 4 + r;
        if (row < n) {
          float t = a[r] + bval;
          if (ADDMEAN) t += meanb[(size_t)row * DO + col];
          if (ACT == ACT_TANH) t = tanhf(t);
          else if (ACT == ACT_LEAKY) t = (t > 0.f) ? t : 0.01f * t;
          out[(size_t)row * DO + col] = t;
          if (out2) out2[(size_t)row * DO + col] = t;
        }
      }
    }
}

// y4[node] = hB[node] @ Wl^T (3 outputs, padded float4); wave per node
__global__ __launch_bounds__(256) void dec4_pre_kernel(
    const float* __restrict__ hB, const float* __restrict__ Wl,
    float* __restrict__ y4, int n) {
  const int node = blockIdx.x * 4 + (threadIdx.x >> 6);
  const int lane = threadIdx.x & 63;
  if (node >= n) return;
  float v = hB[(size_t)node * 64 + lane];
  float p0 = v * Wl[lane];
  float p1 = v * Wl[64 + lane];
  float p2 = v * Wl[128 + lane];
#pragma unroll
  for (int off = 32; off >= 1; off >>= 1) {
    p0 += __shfl_xor(p0, off);
    p1 += __shfl_xor(p1, off);
    p2 += __shfl_xor(p2, off);
  }
  if (lane == 0) ((float4*)y4)[node] = make_float4(p0, p1, p2, 0.f);
}

// out = mean4 + b + hB@Wr^T, scattered layout (z2[:,:2], z2[:,2]); wave/node
__global__ __launch_bounds__(256) void dec4_final_kernel(
    const float* __restrict__ hB, const float* __restrict__ mean4,
    const float* __restrict__ Wr, const float* __restrict__ bias,
    float* __restrict__ out, int n) {
  const int node = blockIdx.x * 4 + (threadIdx.x >> 6);
  const int lane = threadIdx.x & 63;
  if (node >= n) return;
  float v = hB[(size_t)node * 64 + lane];
  float p0 = v * Wr[lane];
  float p1 = v * Wr[64 + lane];
  float p2 = v * Wr[128 + lane];
#pragma unroll
  for (int off = 32; off >= 1; off >>= 1) {
    p0 += __shfl_xor(p0, off);
    p1 += __shfl_xor(p1, off);
    p2 += __shfl_xor(p2, off);
  }
  if (lane == 0) {
    float4 m = ((const float4*)mean4)[node];
    out[2 * (size_t)node]     = p0 + m.x + bias[0];
    out[2 * (size_t)node + 1] = p1 + m.y + bias[1];
    out[2 * (size_t)n + node] = p2 + m.z + bias[2];
  }
}

extern "C" void kernel_launch(void* const* d_in, const int* in_sizes, int n_in,
                              void* d_out, int out_size, void* d_ws, size_t ws_size,
                              hipStream_t stream) {
  const float* x = (const float*)d_in[0];
  const int* ei = (const int*)d_in[1];
  const int N = in_sizes[0] / 64;
  const int E = in_sizes[1] / 2;
  const int* src = ei;
  const int* dst = ei + E;
  const float* g1Wl = (const float*)d_in[2];
  const float* g1b  = (const float*)d_in[3];
  const float* g1Wr = (const float*)d_in[4];
  const float* g2Wl = (const float*)d_in[5];
  const float* g2b  = (const float*)d_in[6];
  const float* g2Wr = (const float*)d_in[7];
  const float* g3Wl = (const float*)d_in[8];
  const float* g3b  = (const float*)d_in[9];
  const float* g3Wr = (const float*)d_in[10];
  const float* t2W  = (const float*)d_in[11];
  const float* t2b  = (const float*)d_in[12];
  const float* d1W  = (const float*)d_in[13];
  const float* d1b  = (const float*)d_in[14];
  const float* d2Wl = (const float*)d_in[15];
  const float* d2b  = (const float*)d_in[16];
  const float* d2Wr = (const float*)d_in[17];
  const float* d3Wl = (const float*)d_in[18];
  const float* d3b  = (const float*)d_in[19];
  const float* d3Wr = (const float*)d_in[20];
  const float* d4Wl = (const float*)d_in[21];
  const float* d4b  = (const float*)d_in[22];
  const float* d4Wr = (const float*)d_in[23];

  float* ws = (float*)d_ws;
  const size_t N128 = (size_t)N * 128;
  float* hA   = ws;                        // N x 128
  float* hB   = ws + N128;                 // N x 128
  float* mean = ws + 2 * N128;             // N x 128 (also hosts y3/mean3, y4/mean4)
  int*   cnt  = (int*)(ws + 3 * N128);     // N
  float* inv  = ws + 3 * N128 + N;         // N
  int*   rowp = (int*)(ws + 3 * N128 + 2 * (size_t)N);      // N+1
  int*   curs = (int*)(ws + 3 * N128 + 3 * (size_t)N + 1);  // N
  int*   esrc = (int*)(ws + 3 * N128 + 4 * (size_t)N + 2);  // E

  float* y3    = mean;                   // N x 64
  float* mean3 = mean + (size_t)N * 64;  // N x 64
  float* y4    = mean;                   // N x 4
  float* mean4 = mean + (size_t)N * 4;   // N x 4

  float* out = (float*)d_out;
  float* mu  = out + 3 * (size_t)N;  // N x 64
  float* lv  = mu + 64 * (size_t)N;  // N x 64 (logvar == mu)

  const int NB = (N + 127) / 128;
  const int GB = (N + 3) / 4;

  // --- CSR build ---
  hipMemsetAsync(cnt, 0, (size_t)N * sizeof(int), stream);
  count_kernel<<<(E + 255) / 256, 256, 0, stream>>>(dst, cnt, E);
  scan_kernel<<<1, 1024, 0, stream>>>(cnt, rowp, curs, inv, N);
  fill_kernel<<<(E + 255) / 256, 256, 0, stream>>>(src, dst, curs, esrc, E);

  // ggn1: x(64) -> hA(128), tanh
  gather_mean_kernel<64><<<GB, 256, 0, stream>>>(x, esrc, rowp, inv, mean, N);
  node_mfma_kernel<64, 128, ACT_TANH, true, false, true><<<NB, 256, 0, stream>>>(
      x, mean, g1Wl, g1Wr, g1b, hA, nullptr, N);

  // ggn2: hA -> hB, tanh
  gather_mean_kernel<128><<<GB, 256, 0, stream>>>(hA, esrc, rowp, inv, mean, N);
  node_mfma_kernel<128, 128, ACT_TANH, true, false, true><<<NB, 256, 0, stream>>>(
      hA, mean, g2Wl, g2Wr, g2b, hB, nullptr, N);

  // ggn3: hB -> hA, tanh
  gather_mean_kernel<128><<<GB, 256, 0, stream>>>(hB, esrc, rowp, inv, mean, N);
  node_mfma_kernel<128, 128, ACT_TANH, true, false, true><<<NB, 256, 0, stream>>>(
      hB, mean, g3Wl, g3Wr, g3b, hA, nullptr, N);

  // tr2: hA(128) -> mu(64) and logvar(64)
  node_mfma_kernel<128, 64, ACT_NONE, false, false, true><<<NB, 256, 0, stream>>>(
      hA, nullptr, nullptr, t2W, t2b, mu, lv, N);

  // dec1: mu(64) -> hB(128), leaky
  node_mfma_kernel<64, 128, ACT_LEAKY, false, false, true><<<NB, 256, 0, stream>>>(
      mu, nullptr, nullptr, d1W, d1b, hB, nullptr, N);

  // dec2: hB -> hA, leaky
  gather_mean_kernel<128><<<GB, 256, 0, stream>>>(hB, esrc, rowp, inv, mean, N);
  node_mfma_kernel<128, 128, ACT_LEAKY, true, false, true><<<NB, 256, 0, stream>>>(
      hB, mean, d2Wl, d2Wr, d2b, hA, nullptr, N);

  // dec3 (linearity): y3 = hA@Wl^T; gather y3 -> mean3; hB = tanh(mean3 + hA@Wr + b)
  node_mfma_kernel<128, 64, ACT_NONE, false, false, false><<<NB, 256, 0, stream>>>(
      hA, nullptr, nullptr, d3Wl, nullptr, y3, nullptr, N);
  gather_mean_kernel<64><<<GB, 256, 0, stream>>>(y3, esrc, rowp, inv, mean3, N);
  node_mfma_kernel<128, 64, ACT_TANH, false, true, true><<<NB, 256, 0, stream>>>(
      hA, mean3, nullptr, d3Wr, d3b, hB, nullptr, N);

  // dec4 (linearity): y4 = hB@Wl^T (3-pad-4); gather4; out = mean4 + b + hB@Wr
  dec4_pre_kernel<<<GB, 256, 0, stream>>>(hB, d4Wl, y4, N);
  gather_mean4_kernel<<<(N + 255) / 256, 256, 0, stream>>>(y4, esrc, rowp, inv, mean4, N);
  dec4_final_kernel<<<GB, 256, 0, stream>>>(hB, mean4, d4Wr, d4b, out, N);
}

// Round 9
// 1153.327 us; speedup vs baseline: 12.5067x; 1.0660x over previous
//
#include <hip/hip_runtime.h>
#include <cmath>

// ---------------------------------------------------------------------------
// GCN_Message: graph VAE forward. Round 9:
//   - Encoder gathers (ggn1-3 -> mu): fp32 (R6-verified; R7/R8 showed the
//     encoder path cannot tolerate shadow quantization -> mu fails ~9e-3).
//   - Decoder gathers (dec2, dec3): fp16 shadows (validated by z2 passing in
//     R7/R8 under strictly worse upstream error).
//   - CSR build: merged count+rank, scan, atomic-free scatter (exact ints).
//   - node GEMMs: MFMA 16x16x32 bf16, 3-term split-bf16 (R6-verified).
// ---------------------------------------------------------------------------

constexpr int ACT_NONE = 0, ACT_TANH = 1, ACT_LEAKY = 2;

typedef __attribute__((ext_vector_type(8))) __bf16 bf16x8;
typedef __attribute__((ext_vector_type(4))) float f32x4;

__device__ __forceinline__ unsigned short f2h(float x) {
  _Float16 h = (_Float16)x;
  unsigned short u;
  __builtin_memcpy(&u, &h, 2);
  return u;
}
__device__ __forceinline__ float hlo(unsigned int u) {
  unsigned short s = (unsigned short)(u & 0xffffu);
  _Float16 h;
  __builtin_memcpy(&h, &s, 2);
  return (float)h;
}
__device__ __forceinline__ float hhi(unsigned int u) {
  unsigned short s = (unsigned short)(u >> 16);
  _Float16 h;
  __builtin_memcpy(&h, &s, 2);
  return (float)h;
}

// pass 1: rank[e] = within-segment index; cnt accumulates degrees
__global__ __launch_bounds__(256) void count_rank_kernel(const int* __restrict__ dst,
                                                         int* __restrict__ cnt,
                                                         int* __restrict__ rank, int E) {
  int e = blockIdx.x * 256 + threadIdx.x;
  if (e < E) rank[e] = atomicAdd(&cnt[dst[e]], 1);
}

// single-workgroup exclusive scan over cnt -> rowptr; also inv = 1/max(cnt,1)
__global__ __launch_bounds__(1024) void scan_kernel(const int* __restrict__ cnt,
                                                    int* __restrict__ rowptr,
                                                    float* __restrict__ inv, int n) {
  __shared__ int wsum[17];
  __shared__ int carry_s;
  const int lane = threadIdx.x & 63;
  const int wid = threadIdx.x >> 6;
  if (threadIdx.x == 0) carry_s = 0;
  __syncthreads();
  for (int base = 0; base < n; base += 1024) {
    int i = base + threadIdx.x;
    int v = (i < n) ? cnt[i] : 0;
    if (i < n) inv[i] = 1.0f / (float)(v > 1 ? v : 1);
    int x = v;
#pragma unroll
    for (int off = 1; off < 64; off <<= 1) {
      int t = __shfl_up(x, off);
      if (lane >= off) x += t;
    }
    if (lane == 63) wsum[wid + 1] = x;
    __syncthreads();
    if (threadIdx.x == 0) {
      wsum[0] = carry_s;
      for (int w = 1; w <= 16; ++w) wsum[w] += wsum[w - 1];
      carry_s = wsum[16];
    }
    __syncthreads();
    int excl = wsum[wid] + x - v;
    if (i < n) rowptr[i] = excl;
    __syncthreads();
  }
  if (threadIdx.x == 0) rowptr[n] = carry_s;
}

// pass 2: atomic-free scatter
__global__ __launch_bounds__(256) void scatter_kernel(const int* __restrict__ src,
                                                      const int* __restrict__ dst,
                                                      const int* __restrict__ rowptr,
                                                      const int* __restrict__ rank,
                                                      int* __restrict__ esrc, int E) {
  int e = blockIdx.x * 256 + threadIdx.x;
  if (e < E) esrc[rowptr[dst[e]] + rank[e]] = src[e];
}

// fp32 gather: wave per node, batch-load 64 neighbor indices, shfl broadcast
template <int D>
__global__ __launch_bounds__(256) void gather_mean_kernel(
    const float* __restrict__ in, const int* __restrict__ esrc,
    const int* __restrict__ rowptr, const float* __restrict__ inv,
    float* __restrict__ meanb, int n) {
  const int node = blockIdx.x * 4 + (threadIdx.x >> 6);
  const int lane = threadIdx.x & 63;
  if (node >= n) return;
  const int beg = rowptr[node];
  const int end = rowptr[node + 1];
  const float iv = inv[node];
  if constexpr (D == 128) {
    const float2* base = (const float2*)in;
    float a0x = 0.f, a0y = 0.f, a1x = 0.f, a1y = 0.f;
    float a2x = 0.f, a2y = 0.f, a3x = 0.f, a3y = 0.f;
    for (int b = beg; b < end; b += 64) {
      int m = end - b;
      if (m > 64) m = 64;
      int myi = (lane < m) ? esrc[b + lane] : 0;
      int s = 0;
      for (; s + 4 <= m; s += 4) {
        int i0 = __shfl(myi, s);
        int i1 = __shfl(myi, s + 1);
        int i2 = __shfl(myi, s + 2);
        int i3 = __shfl(myi, s + 3);
        float2 v0 = base[(size_t)i0 * 64 + lane];
        float2 v1 = base[(size_t)i1 * 64 + lane];
        float2 v2 = base[(size_t)i2 * 64 + lane];
        float2 v3 = base[(size_t)i3 * 64 + lane];
        a0x += v0.x; a0y += v0.y;
        a1x += v1.x; a1y += v1.y;
        a2x += v2.x; a2y += v2.y;
        a3x += v3.x; a3y += v3.y;
      }
      for (; s < m; ++s) {
        int i0 = __shfl(myi, s);
        float2 v0 = base[(size_t)i0 * 64 + lane];
        a0x += v0.x; a0y += v0.y;
      }
    }
    float2 r;
    r.x = ((a0x + a1x) + (a2x + a3x)) * iv;
    r.y = ((a0y + a1y) + (a2y + a3y)) * iv;
    ((float2*)meanb)[(size_t)node * 64 + lane] = r;
  } else {
    float a0 = 0.f, a1 = 0.f, a2 = 0.f, a3 = 0.f;
    for (int b = beg; b < end; b += 64) {
      int m = end - b;
      if (m > 64) m = 64;
      int myi = (lane < m) ? esrc[b + lane] : 0;
      int s = 0;
      for (; s + 4 <= m; s += 4) {
        int i0 = __shfl(myi, s);
        int i1 = __shfl(myi, s + 1);
        int i2 = __shfl(myi, s + 2);
        int i3 = __shfl(myi, s + 3);
        a0 += in[(size_t)i0 * 64 + lane];
        a1 += in[(size_t)i1 * 64 + lane];
        a2 += in[(size_t)i2 * 64 + lane];
        a3 += in[(size_t)i3 * 64 + lane];
      }
      for (; s < m; ++s) {
        int i0 = __shfl(myi, s);
        a0 += in[(size_t)i0 * 64 + lane];
      }
    }
    meanb[(size_t)node * 64 + lane] = ((a0 + a1) + (a2 + a3)) * iv;
  }
}

// fp16 gather (decoder path): wave per node. D=128: lane holds 1 uint.
// D=64: half-wave per neighbor-pair member.
template <int D>
__global__ __launch_bounds__(256) void gather_h_kernel(
    const unsigned short* __restrict__ inh, const int* __restrict__ esrc,
    const int* __restrict__ rowptr, const float* __restrict__ inv,
    float* __restrict__ meanb, int n) {
  const int node = blockIdx.x * 4 + (threadIdx.x >> 6);
  const int lane = threadIdx.x & 63;
  if (node >= n) return;
  const int beg = rowptr[node];
  const int end = rowptr[node + 1];
  const float iv = inv[node];
  const unsigned int* bu = (const unsigned int*)inh;
  if constexpr (D == 128) {
    float a0x = 0.f, a0y = 0.f, a1x = 0.f, a1y = 0.f;
    float a2x = 0.f, a2y = 0.f, a3x = 0.f, a3y = 0.f;
    for (int b = beg; b < end; b += 64) {
      int m = end - b;
      if (m > 64) m = 64;
      int myi = (lane < m) ? esrc[b + lane] : 0;
      int s = 0;
      for (; s + 4 <= m; s += 4) {
        int i0 = __shfl(myi, s);
        int i1 = __shfl(myi, s + 1);
        int i2 = __shfl(myi, s + 2);
        int i3 = __shfl(myi, s + 3);
        unsigned int u0 = bu[(size_t)i0 * 64 + lane];
        unsigned int u1 = bu[(size_t)i1 * 64 + lane];
        unsigned int u2 = bu[(size_t)i2 * 64 + lane];
        unsigned int u3 = bu[(size_t)i3 * 64 + lane];
        a0x += hlo(u0); a0y += hhi(u0);
        a1x += hlo(u1); a1y += hhi(u1);
        a2x += hlo(u2); a2y += hhi(u2);
        a3x += hlo(u3); a3y += hhi(u3);
      }
      for (; s < m; ++s) {
        int i0 = __shfl(myi, s);
        unsigned int u0 = bu[(size_t)i0 * 64 + lane];
        a0x += hlo(u0); a0y += hhi(u0);
      }
    }
    float2 r;
    r.x = ((a0x + a1x) + (a2x + a3x)) * iv;
    r.y = ((a0y + a1y) + (a2y + a3y)) * iv;
    ((float2*)meanb)[(size_t)node * 64 + lane] = r;
  } else {
    const int half = lane >> 5;
    const int hl = lane & 31;
    float ax = 0.f, ay = 0.f, bx = 0.f, by = 0.f;
    for (int b = beg; b < end; b += 64) {
      int m = end - b;
      if (m > 64) m = 64;
      int myi = (lane < m) ? esrc[b + lane] : 0;
      int s = 0;
      for (; s + 4 <= m; s += 4) {
        int i0 = __shfl(myi, s + half);
        int i1 = __shfl(myi, s + 2 + half);
        unsigned int u0 = bu[(size_t)i0 * 32 + hl];
        unsigned int u1 = bu[(size_t)i1 * 32 + hl];
        ax += hlo(u0); ay += hhi(u0);
        bx += hlo(u1); by += hhi(u1);
      }
      for (; s < m; s += 2) {
        int t = s + half;
        if (t < m) {
          int i0 = __shfl(myi, t);
          unsigned int u0 = bu[(size_t)i0 * 32 + hl];
          ax += hlo(u0); ay += hhi(u0);
        }
      }
    }
    float sx = ax + bx, sy = ay + by;
    sx += __shfl_xor(sx, 32);
    sy += __shfl_xor(sy, 32);
    if (half == 0)
      ((float2*)meanb)[(size_t)node * 32 + hl] = make_float2(sx * iv, sy * iv);
  }
}

// thread per node: mean over 4-wide (padded float4) rows
__global__ __launch_bounds__(256) void gather_mean4_kernel(
    const float* __restrict__ y4, const int* __restrict__ esrc,
    const int* __restrict__ rowptr, const float* __restrict__ inv,
    float* __restrict__ mean4, int n) {
  int i = blockIdx.x * 256 + threadIdx.x;
  if (i >= n) return;
  const int beg = rowptr[i], end = rowptr[i + 1];
  const float iv = inv[i];
  float sx = 0.f, sy = 0.f, sz = 0.f;
  const float4* b = (const float4*)y4;
  for (int j = beg; j < end; ++j) {
    float4 v = b[esrc[j]];
    sx += v.x; sy += v.y; sz += v.z;
  }
  ((float4*)mean4)[i] = make_float4(sx * iv, sy * iv, sz * iv, 0.f);
}

__device__ __forceinline__ void split_bf16(float x, __bf16& h, __bf16& l) {
  h = (__bf16)x;
  l = (__bf16)(x - (float)h);
}

// out[row,col] = act( (AGG ? mean@Wl^T : 0) + (ADDMEAN ? mean : 0)
//                     + in@Wr^T + (BIAS ? b : 0) )
// MFMA 16x16x32 bf16, 3-term split emulation. Optional fp32 out/out2 and
// fp16 shadow outh.
template <int DI, int DO, int ACT, bool AGG, bool ADDMEAN, bool BIAS>
__global__ __launch_bounds__(256) void node_mfma_kernel(
    const float* __restrict__ in, const float* __restrict__ meanb,
    const float* __restrict__ Wl, const float* __restrict__ Wr,
    const float* __restrict__ bias, float* __restrict__ out,
    float* __restrict__ out2, unsigned short* __restrict__ outh, int n) {
  constexpr int BM = 128;
  constexpr int KC = 32;
  constexpr int KS = 40;       // padded k-stride in bf16 elems
  constexpr int CT = DO / 16;  // col tiles per wave
  __shared__ __align__(16) __bf16 As_hi[BM * KS];
  __shared__ __align__(16) __bf16 As_lo[BM * KS];
  __shared__ __align__(16) __bf16 Ws_hi[DO * KS];
  __shared__ __align__(16) __bf16 Ws_lo[DO * KS];

  const int wv = threadIdx.x >> 6;
  const int lane = threadIdx.x & 63;
  const int lm = lane & 15;
  const int lq = lane >> 4;
  const int row0 = blockIdx.x * BM;

  f32x4 acc[2][CT];
#pragma unroll
  for (int rt = 0; rt < 2; ++rt)
#pragma unroll
    for (int ct = 0; ct < CT; ++ct) acc[rt][ct] = (f32x4){0.f, 0.f, 0.f, 0.f};

  const int nphase = AGG ? 2 : 1;
  for (int phase = 0; phase < nphase; ++phase) {
    const float* W = (phase == 0) ? Wr : Wl;
    const float* Amat = (phase == 0) ? in : meanb;
    for (int k0 = 0; k0 < DI; k0 += KC) {
      {
        const int r = threadIdx.x >> 1;
        const int kb = (threadIdx.x & 1) * 16;
        const int row = row0 + r;
        float v[16];
        if (row < n) {
          const float4* p = (const float4*)(Amat + (size_t)row * DI + k0 + kb);
#pragma unroll
          for (int i = 0; i < 4; ++i) {
            float4 t = p[i];
            v[4 * i + 0] = t.x; v[4 * i + 1] = t.y;
            v[4 * i + 2] = t.z; v[4 * i + 3] = t.w;
          }
        } else {
#pragma unroll
          for (int i = 0; i < 16; ++i) v[i] = 0.f;
        }
        bf16x8 hi[2], lo[2];
#pragma unroll
        for (int g = 0; g < 2; ++g)
#pragma unroll
          for (int i = 0; i < 8; ++i) {
            __bf16 h, l;
            split_bf16(v[g * 8 + i], h, l);
            hi[g][i] = h; lo[g][i] = l;
          }
        *(bf16x8*)(&As_hi[r * KS + kb]) = hi[0];
        *(bf16x8*)(&As_hi[r * KS + kb + 8]) = hi[1];
        *(bf16x8*)(&As_lo[r * KS + kb]) = lo[0];
        *(bf16x8*)(&As_lo[r * KS + kb + 8]) = lo[1];
      }
      if constexpr (DO == 128) {
        const int c = threadIdx.x >> 1;
        const int kb = (threadIdx.x & 1) * 16;
        const float4* p = (const float4*)(W + (size_t)c * DI + k0 + kb);
        float v[16];
#pragma unroll
        for (int i = 0; i < 4; ++i) {
          float4 t = p[i];
          v[4 * i + 0] = t.x; v[4 * i + 1] = t.y;
          v[4 * i + 2] = t.z; v[4 * i + 3] = t.w;
        }
        bf16x8 hi[2], lo[2];
#pragma unroll
        for (int g = 0; g < 2; ++g)
#pragma unroll
          for (int i = 0; i < 8; ++i) {
            __bf16 h, l;
            split_bf16(v[g * 8 + i], h, l);
            hi[g][i] = h; lo[g][i] = l;
          }
        *(bf16x8*)(&Ws_hi[c * KS + kb]) = hi[0];
        *(bf16x8*)(&Ws_hi[c * KS + kb + 8]) = hi[1];
        *(bf16x8*)(&Ws_lo[c * KS + kb]) = lo[0];
        *(bf16x8*)(&Ws_lo[c * KS + kb + 8]) = lo[1];
      } else {
        const int c = threadIdx.x >> 2;
        const int kb = (threadIdx.x & 3) * 8;
        const float4* p = (const float4*)(W + (size_t)c * DI + k0 + kb);
        float v[8];
#pragma unroll
        for (int i = 0; i < 2; ++i) {
          float4 t = p[i];
          v[4 * i + 0] = t.x; v[4 * i + 1] = t.y;
          v[4 * i + 2] = t.z; v[4 * i + 3] = t.w;
        }
        bf16x8 hi, lo;
#pragma unroll
        for (int i = 0; i < 8; ++i) {
          __bf16 h, l;
          split_bf16(v[i], h, l);
          hi[i] = h; lo[i] = l;
        }
        *(bf16x8*)(&Ws_hi[c * KS + kb]) = hi;
        *(bf16x8*)(&Ws_lo[c * KS + kb]) = lo;
      }
      __syncthreads();
      const int kb = lq * 8;
      bf16x8 ah[2], al[2];
#pragma unroll
      for (int rt = 0; rt < 2; ++rt) {
        const int r = wv * 32 + rt * 16 + lm;
        ah[rt] = *(const bf16x8*)(&As_hi[r * KS + kb]);
        al[rt] = *(const bf16x8*)(&As_lo[r * KS + kb]);
      }
#pragma unroll
      for (int ct = 0; ct < CT; ++ct) {
        const int c = ct * 16 + lm;
        bf16x8 bh = *(const bf16x8*)(&Ws_hi[c * KS + kb]);
        bf16x8 bl = *(const bf16x8*)(&Ws_lo[c * KS + kb]);
#pragma unroll
        for (int rt = 0; rt < 2; ++rt) {
          acc[rt][ct] = __builtin_amdgcn_mfma_f32_16x16x32_bf16(ah[rt], bh, acc[rt][ct], 0, 0, 0);
          acc[rt][ct] = __builtin_amdgcn_mfma_f32_16x16x32_bf16(al[rt], bh, acc[rt][ct], 0, 0, 0);
          acc[rt][ct] = __builtin_amdgcn_mfma_f32_16x16x32_bf16(ah[rt], bl, acc[rt][ct], 0, 0, 0);
        }
      }
      __syncthreads();
    }
  }

#pragma unroll
  for (int rt = 0; rt < 2; ++rt)
#pragma unroll
    for (int ct = 0; ct < CT; ++ct) {
      const int col = ct * 16 + lm;
      const float bval = BIAS ? bias[col] : 0.f;
      f32x4 a = acc[rt][ct];
#pragma unroll
      for (int r = 0; r < 4; ++r) {
        const int row = row0 + wv * 32 + rt * 16 + lq * 4 + r;
        if (row < n) {
          float t = a[r] + bval;
          if (ADDMEAN) t += meanb[(size_t)row * DO + col];
          if (ACT == ACT_TANH) t = tanhf(t);
          else if (ACT == ACT_LEAKY) t = (t > 0.f) ? t : 0.01f * t;
          if (out) out[(size_t)row * DO + col] = t;
          if (out2) out2[(size_t)row * DO + col] = t;
          if (outh) outh[(size_t)row * DO + col] = f2h(t);
        }
      }
    }
}

// y4[node] = hB[node] @ Wl^T (3 outputs, padded float4); wave per node
__global__ __launch_bounds__(256) void dec4_pre_kernel(
    const float* __restrict__ hB, const float* __restrict__ Wl,
    float* __restrict__ y4, int n) {
  const int node = blockIdx.x * 4 + (threadIdx.x >> 6);
  const int lane = threadIdx.x & 63;
  if (node >= n) return;
  float v = hB[(size_t)node * 64 + lane];
  float p0 = v * Wl[lane];
  float p1 = v * Wl[64 + lane];
  float p2 = v * Wl[128 + lane];
#pragma unroll
  for (int off = 32; off >= 1; off >>= 1) {
    p0 += __shfl_xor(p0, off);
    p1 += __shfl_xor(p1, off);
    p2 += __shfl_xor(p2, off);
  }
  if (lane == 0) ((float4*)y4)[node] = make_float4(p0, p1, p2, 0.f);
}

// out = mean4 + b + hB@Wr^T, scattered layout (z2[:,:2], z2[:,2]); wave/node
__global__ __launch_bounds__(256) void dec4_final_kernel(
    const float* __restrict__ hB, const float* __restrict__ mean4,
    const float* __restrict__ Wr, const float* __restrict__ bias,
    float* __restrict__ out, int n) {
  const int node = blockIdx.x * 4 + (threadIdx.x >> 6);
  const int lane = threadIdx.x & 63;
  if (node >= n) return;
  float v = hB[(size_t)node * 64 + lane];
  float p0 = v * Wr[lane];
  float p1 = v * Wr[64 + lane];
  float p2 = v * Wr[128 + lane];
#pragma unroll
  for (int off = 32; off >= 1; off >>= 1) {
    p0 += __shfl_xor(p0, off);
    p1 += __shfl_xor(p1, off);
    p2 += __shfl_xor(p2, off);
  }
  if (lane == 0) {
    float4 m = ((const float4*)mean4)[node];
    out[2 * (size_t)node]     = p0 + m.x + bias[0];
    out[2 * (size_t)node + 1] = p1 + m.y + bias[1];
    out[2 * (size_t)n + node] = p2 + m.z + bias[2];
  }
}

extern "C" void kernel_launch(void* const* d_in, const int* in_sizes, int n_in,
                              void* d_out, int out_size, void* d_ws, size_t ws_size,
                              hipStream_t stream) {
  const float* x = (const float*)d_in[0];
  const int* ei = (const int*)d_in[1];
  const int N = in_sizes[0] / 64;
  const int E = in_sizes[1] / 2;
  const int* src = ei;
  const int* dst = ei + E;
  const float* g1Wl = (const float*)d_in[2];
  const float* g1b  = (const float*)d_in[3];
  const float* g1Wr = (const float*)d_in[4];
  const float* g2Wl = (const float*)d_in[5];
  const float* g2b  = (const float*)d_in[6];
  const float* g2Wr = (const float*)d_in[7];
  const float* g3Wl = (const float*)d_in[8];
  const float* g3b  = (const float*)d_in[9];
  const float* g3Wr = (const float*)d_in[10];
  const float* t2W  = (const float*)d_in[11];
  const float* t2b  = (const float*)d_in[12];
  const float* d1W  = (const float*)d_in[13];
  const float* d1b  = (const float*)d_in[14];
  const float* d2Wl = (const float*)d_in[15];
  const float* d2b  = (const float*)d_in[16];
  const float* d2Wr = (const float*)d_in[17];
  const float* d3Wl = (const float*)d_in[18];
  const float* d3b  = (const float*)d_in[19];
  const float* d3Wr = (const float*)d_in[20];
  const float* d4Wl = (const float*)d_in[21];
  const float* d4b  = (const float*)d_in[22];
  const float* d4Wr = (const float*)d_in[23];

  float* ws = (float*)d_ws;
  const size_t N128 = (size_t)N * 128;
  float* hA   = ws;                        // N x 128 f32
  float* hB   = ws + N128;                 // N x 128 f32
  float* mean = ws + 2 * N128;             // N x 128 f32 (also y4/mean4)
  int*   cnt  = (int*)(ws + 3 * N128);                        // N
  float* inv  = ws + 3 * N128 + N;                            // N
  int*   rowp = (int*)(ws + 3 * N128 + 2 * (size_t)N);        // N+1
  int*   rank = (int*)(ws + 3 * N128 + 3 * (size_t)N + 1);    // E
  int*   esrc = rank + E;                                     // E
  unsigned short* shB = (unsigned short*)(esrc + E);          // N x 128 fp16
  unsigned short* shC = shB + N128;                           // N x 64 fp16

  float* y4    = mean;                   // N x 4
  float* mean4 = mean + (size_t)N * 4;   // N x 4

  float* out = (float*)d_out;
  float* mu  = out + 3 * (size_t)N;  // N x 64
  float* lv  = mu + 64 * (size_t)N;  // N x 64 (logvar == mu)

  const int NB = (N + 127) / 128;
  const int GB = (N + 3) / 4;

  // --- CSR build: one atomic round + scan + atomic-free scatter ---
  hipMemsetAsync(cnt, 0, (size_t)N * sizeof(int), stream);
  count_rank_kernel<<<(E + 255) / 256, 256, 0, stream>>>(dst, cnt, rank, E);
  scan_kernel<<<1, 1024, 0, stream>>>(cnt, rowp, inv, N);
  scatter_kernel<<<(E + 255) / 256, 256, 0, stream>>>(src, dst, rowp, rank, esrc, E);

  // ggn1: x(64) -> hA(128), tanh  [fp32 gather]
  gather_mean_kernel<64><<<GB, 256, 0, stream>>>(x, esrc, rowp, inv, mean, N);
  node_mfma_kernel<64, 128, ACT_TANH, true, false, true><<<NB, 256, 0, stream>>>(
      x, mean, g1Wl, g1Wr, g1b, hA, nullptr, nullptr, N);

  // ggn2: hA -> hB, tanh  [fp32 gather]
  gather_mean_kernel<128><<<GB, 256, 0, stream>>>(hA, esrc, rowp, inv, mean, N);
  node_mfma_kernel<128, 128, ACT_TANH, true, false, true><<<NB, 256, 0, stream>>>(
      hA, mean, g2Wl, g2Wr, g2b, hB, nullptr, nullptr, N);

  // ggn3: hB -> hA, tanh  [fp32 gather]
  gather_mean_kernel<128><<<GB, 256, 0, stream>>>(hB, esrc, rowp, inv, mean, N);
  node_mfma_kernel<128, 128, ACT_TANH, true, false, true><<<NB, 256, 0, stream>>>(
      hB, mean, g3Wl, g3Wr, g3b, hA, nullptr, nullptr, N);

  // tr2: hA(128) -> mu(64) and logvar(64)
  node_mfma_kernel<128, 64, ACT_NONE, false, false, true><<<NB, 256, 0, stream>>>(
      hA, nullptr, nullptr, t2W, t2b, mu, lv, nullptr, N);

  // dec1: mu(64) -> hB(128), leaky  [fp16 shadow shB for dec2 gather]
  node_mfma_kernel<64, 128, ACT_LEAKY, false, false, true><<<NB, 256, 0, stream>>>(
      mu, nullptr, nullptr, d1W, d1b, hB, nullptr, shB, N);

  // dec2: hB -> hA, leaky  [fp16 gather]
  gather_h_kernel<128><<<GB, 256, 0, stream>>>(shB, esrc, rowp, inv, mean, N);
  node_mfma_kernel<128, 128, ACT_LEAKY, true, false, true><<<NB, 256, 0, stream>>>(
      hB, mean, d2Wl, d2Wr, d2b, hA, nullptr, nullptr, N);

  // dec3 (linearity): y3h = fp16(hA@Wl^T); gather -> mean; hB = tanh(mean + hA@Wr + b)
  node_mfma_kernel<128, 64, ACT_NONE, false, false, false><<<NB, 256, 0, stream>>>(
      hA, nullptr, nullptr, d3Wl, nullptr, nullptr, nullptr, shC, N);
  gather_h_kernel<64><<<GB, 256, 0, stream>>>(shC, esrc, rowp, inv, mean, N);
  node_mfma_kernel<128, 64, ACT_TANH, false, true, true><<<NB, 256, 0, stream>>>(
      hA, mean, nullptr, d3Wr, d3b, hB, nullptr, nullptr, N);

  // dec4 (linearity, fp32): y4 = hB@Wl^T (3-pad-4); gather4; out = mean4 + b + hB@Wr
  dec4_pre_kernel<<<GB, 256, 0, stream>>>(hB, d4Wl, y4, N);
  gather_mean4_kernel<<<(N + 255) / 256, 256, 0, stream>>>(y4, esrc, rowp, inv, mean4, N);
  dec4_final_kernel<<<GB, 256, 0, stream>>>(hB, mean4, d4Wr, d4b, out, N);
}